// Round 8
// baseline (1034.675 us; speedup 1.0000x reference)
//
#include <hip/hip_runtime.h>

typedef unsigned short u16;
typedef __attribute__((ext_vector_type(8))) __bf16 bf16x8;
typedef __attribute__((ext_vector_type(8))) unsigned short ushort8;
typedef __attribute__((ext_vector_type(4))) float f32x4;

__device__ __forceinline__ float bf2f(u16 u) { return __uint_as_float(((unsigned)u) << 16); }
__device__ __forceinline__ u16 f2bf(float f) {
    unsigned x = __float_as_uint(f);
    x += 0x7fffu + ((x >> 16) & 1u);
    return (u16)(x >> 16);
}
__device__ __forceinline__ u16 f2h16(float f) {
    _Float16 h = (_Float16)f; u16 r; __builtin_memcpy(&r, &h, 2); return r;
}
__device__ __forceinline__ float h162f(u16 u) {
    _Float16 h; __builtin_memcpy(&h, &u, 2); return (float)h;
}

// Padded l-space: per-scale (HS+2) rows x W' cols with zero border, W' mult of 8.
// scale0: HS=64 W=72 off=0      (66*72=4752)
// scale1: HS=57 W=64 off=4752   (59*64=3776)
// scale2: HS=51 W=56 off=8528   (53*56=2968)
// scale3: HS=44 W=48 off=11496  (46*48=2208) -> 13704, dead zone to LP=13824
#define LP 13824

// ---------------------------------------------------------------------------
// GEMM: C[M,N] = A[M,K] * B[N,K]^T  (bf16 in, fp32 acc), 128x128 tile, BK=32.
// ---------------------------------------------------------------------------
__global__ __launch_bounds__(256) void d7_gemm(
    const u16* __restrict__ A, const u16* __restrict__ B,
    int N, int K, int kLen, int mTiles, int S,
    long aBS, long bBS,
    const float* __restrict__ bias, const float* __restrict__ alpha, int act,
    const float* __restrict__ resid, long residBS,
    float* __restrict__ outF, long oFBS,
    u16* __restrict__ outB, long oBBS,
    u16* __restrict__ outT, int ldT, long oTBS,
    float* __restrict__ outP, long pMN, int pBf)
{
    __shared__ u16 As[128 * 40];
    __shared__ u16 Bs[128 * 40];

    const int tid = threadIdx.x;
    const int wv = tid >> 6, lane = tid & 63;
    const int wm = wv >> 1, wn = wv & 1;
    const int bn = blockIdx.x;
    const int bm = blockIdx.y % mTiles;
    const int ks = blockIdx.y / mTiles;
    const int z  = blockIdx.z;
    const int kStart = ks * kLen;

    const int srow = tid >> 1;
    const int soff = (tid & 1) * 16;
    const u16* gA = A + z * aBS + (size_t)(bm * 128 + srow) * K + kStart + soff;
    const u16* gB = B + z * bBS + (size_t)(bn * 128 + srow) * K + kStart + soff;
    u16* lA = &As[srow * 40 + soff];
    u16* lB = &Bs[srow * 40 + soff];

    f32x4 acc[4][4] = {};

    for (int k0 = 0; k0 < kLen; k0 += 32) {
        __syncthreads();
        ((uint4*)lA)[0] = ((const uint4*)gA)[0];
        ((uint4*)lA)[1] = ((const uint4*)gA)[1];
        ((uint4*)lB)[0] = ((const uint4*)gB)[0];
        ((uint4*)lB)[1] = ((const uint4*)gB)[1];
        gA += 32; gB += 32;
        __syncthreads();

        bf16x8 a[4], b[4];
        #pragma unroll
        for (int mt = 0; mt < 4; ++mt)
            a[mt] = *reinterpret_cast<const bf16x8*>(&As[(wm * 64 + mt * 16 + (lane & 15)) * 40 + (lane >> 4) * 8]);
        #pragma unroll
        for (int nt = 0; nt < 4; ++nt)
            b[nt] = *reinterpret_cast<const bf16x8*>(&Bs[(wn * 64 + nt * 16 + (lane & 15)) * 40 + (lane >> 4) * 8]);
        #pragma unroll
        for (int mt = 0; mt < 4; ++mt)
            #pragma unroll
            for (int nt = 0; nt < 4; ++nt)
                acc[mt][nt] = __builtin_amdgcn_mfma_f32_16x16x32_bf16(a[mt], b[nt], acc[mt][nt], 0, 0, 0);
    }

    if (outP) {
        const size_t pbase = ((size_t)z * S + ks) * pMN;
        #pragma unroll
        for (int mt = 0; mt < 4; ++mt) {
            const int mg = bm * 128 + wm * 64 + mt * 16 + ((lane >> 4) << 2);
            #pragma unroll
            for (int nt = 0; nt < 4; ++nt) {
                const int ng = bn * 128 + wn * 64 + nt * 16 + (lane & 15);
                if (pBf) {
                    u16* pp = (u16*)outP + pbase;
                    #pragma unroll
                    for (int r = 0; r < 4; ++r)
                        pp[(size_t)(mg + r) * N + ng] = f2bf(acc[mt][nt][r]);
                } else {
                    float* pp = outP + pbase;
                    #pragma unroll
                    for (int r = 0; r < 4; ++r)
                        pp[(size_t)(mg + r) * N + ng] = acc[mt][nt][r];
                }
            }
        }
        return;
    }

    const float avalS = (act == 1) ? alpha[0] : 0.0f;
    #pragma unroll
    for (int mt = 0; mt < 4; ++mt) {
        const int mg = bm * 128 + wm * 64 + mt * 16 + ((lane >> 4) << 2);
        float bv[4] = {0.f, 0.f, 0.f, 0.f}, av[4];
        if (bias) {
            #pragma unroll
            for (int r = 0; r < 4; ++r) bv[r] = bias[mg + r];
        }
        if (act == 3) {
            #pragma unroll
            for (int r = 0; r < 4; ++r) av[r] = alpha[mg + r];
        }
        #pragma unroll
        for (int nt = 0; nt < 4; ++nt) {
            const int ng = bn * 128 + wn * 64 + nt * 16 + (lane & 15);
            float v[4];
            #pragma unroll
            for (int r = 0; r < 4; ++r) {
                float t = acc[mt][nt][r] + bv[r];
                if (act == 1) t = (t >= 0.f) ? t : avalS * t;
                else if (act == 2) t = fmaxf(t, 0.f);
                else if (act == 3) t = (t >= 0.f) ? t : av[r] * t;
                if (resid) t += resid[z * residBS + (size_t)(mg + r) * N + ng];
                v[r] = t;
            }
            if (outF) {
                #pragma unroll
                for (int r = 0; r < 4; ++r) outF[z * oFBS + (size_t)(mg + r) * N + ng] = v[r];
            }
            if (outB) {
                #pragma unroll
                for (int r = 0; r < 4; ++r) outB[z * oBBS + (size_t)(mg + r) * N + ng] = f2bf(v[r]);
            }
            if (outT) {
                unsigned long long pk = (unsigned long long)f2bf(v[0])
                    | ((unsigned long long)f2bf(v[1]) << 16)
                    | ((unsigned long long)f2bf(v[2]) << 32)
                    | ((unsigned long long)f2bf(v[3]) << 48);
                *reinterpret_cast<unsigned long long*>(outT + z * oTBS + (size_t)ng * ldT + mg) = pk;
            }
        }
    }
}

// split-K reduce + bias/act/resid epilogue; N fixed 4096 (m = i>>12)
__global__ __launch_bounds__(256) void d7_epi(
    const void* __restrict__ parts, int S, long sStride, long bStride,
    const float* __restrict__ bias, const float* __restrict__ alpha, int act,
    const float* __restrict__ resid, long residBS, float scale,
    float* __restrict__ out, long outBS, int total, int pBf)
{
    int i = blockIdx.x * 256 + threadIdx.x;
    if (i >= total) return;
    int b = blockIdx.z;
    float s = 0.f;
    if (pBf) {
        const u16* p = (const u16*)parts + b * bStride + i;
        for (int t = 0; t < S; ++t) s += bf2f(p[(size_t)t * sStride]);
    } else {
        const float* p = (const float*)parts + b * bStride + i;
        for (int t = 0; t < S; ++t) s += p[(size_t)t * sStride];
    }
    s *= scale;
    if (bias) s += bias[i >> 12];
    if (act == 1) { float a = alpha[0]; s = (s >= 0.f) ? s : a * s; }
    else if (act == 2) s = fmaxf(s, 0.f);
    if (resid) s += resid[b * residBS + i];
    out[b * outBS + i] = s;
}

// ---------------------------------------------------------------------------
__global__ __launch_bounds__(256) void d7_cast(const float* __restrict__ src, u16* __restrict__ dst, int n) {
    int i = blockIdx.x * 256 + threadIdx.x;
    if (i < n) dst[i] = f2bf(src[i]);
}

__global__ __launch_bounds__(256) void d7_wbuild(
    const float* __restrict__ pamb_w, const float* __restrict__ pam_w, const float* __restrict__ paa_w,
    const float* __restrict__ pamb_b, const float* __restrict__ pam_b, const float* __restrict__ paa_b,
    const float* __restrict__ pamb_a, const float* __restrict__ pam_a, const float* __restrict__ paa_a,
    u16* __restrict__ W1, u16* __restrict__ W2,
    float* __restrict__ b1, float* __restrict__ a1,
    float* __restrict__ b2, float* __restrict__ a2)
{
    int i = blockIdx.x * 256 + threadIdx.x;
    if (i < 256 * 128) {
        int r = i >> 7, c = i & 127;
        float w1 = (r < 64) ? pamb_w[r * 128 + c] : (r < 128) ? pam_w[(r - 64) * 128 + c] : paa_w[(r - 128) * 128 + c];
        W1[i] = f2bf(w1);
        float w2 = (r < 64) ? pam_w[r * 128 + c] : (r < 192) ? paa_w[(r - 64) * 128 + c] : 0.f;
        W2[i] = f2bf(w2);
    }
    if (i < 256) {
        int r = i;
        b1[r] = (r < 64) ? pamb_b[r] : (r < 128) ? pam_b[r - 64] : paa_b[r - 128];
        a1[r] = (r < 64) ? pamb_a[0] : (r < 128) ? pam_a[0] : paa_a[0];
        b2[r] = (r < 64) ? pam_b[r] : (r < 192) ? paa_b[r - 64] : 0.f;
        a2[r] = (r < 64) ? pam_a[0] : (r < 192) ? paa_a[0] : 0.f;
    }
}

__global__ __launch_bounds__(256) void d7_maxpool(const float* __restrict__ x, float* __restrict__ out) {
    int p = blockIdx.x * 256 + threadIdx.x;
    int c = blockIdx.y, b = blockIdx.z;
    int oh = p >> 6, ow = p & 63;
    const float* ip = x + ((size_t)b * 64 + c) * 16384;
    float v0 = ip[(2 * oh) * 128 + 2 * ow];
    float v1 = ip[(2 * oh) * 128 + 2 * ow + 1];
    float v2 = ip[(2 * oh + 1) * 128 + 2 * ow];
    float v3 = ip[(2 * oh + 1) * 128 + 2 * ow + 1];
    out[((size_t)b * 64 + c) * 4096 + p] = fmaxf(fmaxf(v0, v1), fmaxf(v2, v3));
}

__global__ __launch_bounds__(256) void d7_im2col(const float* __restrict__ img, u16* __restrict__ patT,
                                                 int Cin, long inBS, long outBS) {
    int K = Cin * 9;
    int k = blockIdx.x * 256 + threadIdx.x;
    if (k >= K) return;
    int p = blockIdx.y, b = blockIdx.z;
    int c = k / 9, k9 = k - c * 9;
    int h = p >> 6, w = p & 63;
    int y = h + k9 / 3 - 1, x = w + (k9 % 3) - 1;
    const float* ip = img + b * inBS;
    float v = (y >= 0 && y < 64 && x >= 0 && x < 64) ? ip[(size_t)c * 4096 + y * 64 + x] : 0.f;
    patT[b * outBS + (size_t)p * K + k] = f2bf(v);
}

// transpose-cast: in fp32 [128][P] -> out bf16 [p][128]
__global__ __launch_bounds__(256) void d7_t32(const float* __restrict__ in, long inBS, int P,
                                              u16* __restrict__ out, long outBS) {
    __shared__ float tile[32][33];
    int p0 = blockIdx.x * 32, c0 = blockIdx.y * 32, b = blockIdx.z;
    int tx = threadIdx.x & 31, ty = threadIdx.x >> 5;
    const float* ip = in + b * inBS;
    #pragma unroll
    for (int i = 0; i < 32; i += 8) {
        int c = c0 + ty + i, p = p0 + tx;
        tile[ty + i][tx] = (p < P) ? ip[(size_t)c * P + p] : 0.f;
    }
    __syncthreads();
    u16* op = out + b * outBS;
    #pragma unroll
    for (int i = 0; i < 32; i += 8) {
        int p = p0 + ty + i, c = c0 + tx;
        if (p < P) op[(size_t)p * 128 + c] = f2bf(tile[tx][ty + i]);
    }
}

// scatter K-major 64-wide rows (+ optional fused s2)
__global__ __launch_bounds__(256) void d7_scK(const u16* __restrict__ cT, long cBS, int ldC, int colBase,
                                              int pOff, int P, int HS, int Wp, int off,
                                              u16* __restrict__ dst, long dBS,
                                              float* __restrict__ s2out) {
    int t = blockIdx.x * 256 + threadIdx.x;
    int p = t >> 3, cg = t & 7;
    if (p >= P) return;
    int b = blockIdx.z;
    ushort8 v = *reinterpret_cast<const ushort8*>(cT + b * cBS + (size_t)(pOff + p) * ldC + colBase + cg * 8);
    int h = p / HS, w = p - h * HS;
    int lp = off + (h + 1) * Wp + w + 1;
    *reinterpret_cast<ushort8*>(dst + b * dBS + (size_t)lp * 64 + cg * 8) = v;
    if (s2out) {
        float ss = 0.f;
        #pragma unroll
        for (int i = 0; i < 8; ++i) { float f = bf2f(v[i]); ss += f * f; }
        ss += __shfl_xor(ss, 1);
        ss += __shfl_xor(ss, 2);
        ss += __shfl_xor(ss, 4);
        if (cg == 0) s2out[(size_t)b * LP + lp] = ss;
    }
}

__global__ __launch_bounds__(256) void d7_scR(const u16* __restrict__ cO, long cBS, int ldC, int rowBase,
                                              int pOff, int P, int HS, int Wp, int off,
                                              u16* __restrict__ dst, long dBS) {
    int p = blockIdx.x * 256 + threadIdx.x;
    if (p >= P) return;
    int co = blockIdx.y, b = blockIdx.z;
    u16 v = cO[b * cBS + (size_t)(rowBase + co) * ldC + pOff + p];
    int h = p / HS, w = p - h * HS;
    int lp = off + (h + 1) * Wp + w + 1;
    dst[b * dBS + (size_t)co * LP + lp] = v;
}

// jax.image.resize bilinear antialias, 64 -> OS
template <int OS>
__device__ __forceinline__ void d7_taps(int o, int& i0, float w3[3]) {
    const float inv = 64.0f / OS;
    float s = (o + 0.5f) * inv - 0.5f;
    i0 = (int)ceilf(s - inv);
    float wsum = 0.f;
    #pragma unroll
    for (int t = 0; t < 3; ++t) {
        int y = i0 + t;
        float wt = 1.0f - fabsf((float)y - s) / inv;
        wt = (wt > 0.f && y >= 0 && y < 64) ? wt : 0.f;
        w3[t] = wt; wsum += wt;
    }
    float r = 1.0f / wsum;
    w3[0] *= r; w3[1] *= r; w3[2] *= r;
}

template <int OS>
__global__ __launch_bounds__(256) void d7_resize(const float* __restrict__ in, float* __restrict__ out, long out_bs) {
    int p = blockIdx.x * 256 + threadIdx.x;
    if (p >= OS * OS) return;
    int c = blockIdx.y, b = blockIdx.z;
    int oh = p / OS, ow = p - oh * OS;
    const float* img = in + ((size_t)b * 128 + c) * 4096;
    int y0, x0; float wy[3], wx[3];
    d7_taps<OS>(oh, y0, wy);
    d7_taps<OS>(ow, x0, wx);
    float sum = 0.f;
    #pragma unroll
    for (int iy = 0; iy < 3; ++iy) {
        if (wy[iy] <= 0.f) continue;
        float rs = 0.f;
        #pragma unroll
        for (int ix = 0; ix < 3; ++ix) {
            if (wx[ix] <= 0.f) continue;
            rs += wx[ix] * img[(y0 + iy) * 64 + (x0 + ix)];
        }
        sum += wy[iy] * rs;
    }
    out[(size_t)b * out_bs + (size_t)c * OS * OS + p] = sum;
}

__device__ __forceinline__ int d7_scaleW(int l) {
    return (l < 4752) ? 72 : (l < 8528) ? 64 : (l < 11496) ? 56 : 48;
}

// rnorm[l'] = interior ? (10*log2e)/max(sqrt(9-tap sum of s2),1e-4) : 0
__global__ __launch_bounds__(256) void d7_rnormk(const float* __restrict__ s2, float* __restrict__ rnorm) {
    int l = blockIdx.x * 256 + threadIdx.x;
    if (l >= LP) return;
    int zb = blockIdx.z;
    int off, W, HS;
    if (l < 4752)       { off = 0;     W = 72; HS = 64; }
    else if (l < 8528)  { off = 4752;  W = 64; HS = 57; }
    else if (l < 11496) { off = 8528;  W = 56; HS = 51; }
    else                { off = 11496; W = 48; HS = 44; }
    int li = l - off, y = li / W, x = li - y * W;
    float v = 0.f;
    if (y >= 1 && y <= HS && x >= 1 && x <= HS) {
        const float* s = s2 + (size_t)zb * LP;
        float a = 0.f;
        #pragma unroll
        for (int dy = -1; dy <= 1; ++dy)
            #pragma unroll
            for (int dx = -1; dx <= 1; ++dx)
                a += s[l + dy * W + dx];
        v = 14.426950408889634f / fmaxf(sqrtf(a), 1e-4f);
    }
    rnorm[(size_t)zb * LP + l] = v;
}

// Fused stencil1 + softmax stats. One block per p-row.
// All 16B loads ALIGNED; +/-1 l-shifts via lane shuffles (edge lanes: 2B load).
// scT fp16 log2-domain (pads -1e4); statM[p] = m + log2(Z).
__global__ __launch_bounds__(256) void d7_st1f(const u16* __restrict__ in, u16* __restrict__ out,
                                               const float* __restrict__ rnorm,
                                               float* __restrict__ statM) {
    const int p = blockIdx.x;
    const int tid = threadIdx.x, wvi = tid >> 6, lane = tid & 63;
    const int h = p >> 6, w = p & 63;
    ushort8 vals16[7];
    float m = -3e38f;
    #pragma unroll
    for (int it = 0; it < 7; ++it) {
        int vg = tid + it * 256;
        if (vg >= LP / 8) continue;                       // whole waves skip (wave-aligned)
        int l8 = vg << 3;
        int W = d7_scaleW(l8);
        float acc[8] = {0.f, 0.f, 0.f, 0.f, 0.f, 0.f, 0.f, 0.f};
        #pragma unroll
        for (int a = -1; a <= 1; ++a) {
            int ph = h + a;
            if ((unsigned)ph >= 64u) continue;
            const u16* rb = in + (size_t)(p + a * 64) * LP + l8 + a * W;   // aligned base, b=0 row
            {
                ushort8 v = *reinterpret_cast<const ushort8*>(rb);
                #pragma unroll
                for (int i = 0; i < 8; ++i) acc[i] += bf2f(v[i]);
            }
            if (w - 1 >= 0) {   // b=-1: row -LP, elements shifted right
                const u16* r1 = rb - LP;
                ushort8 v = *reinterpret_cast<const ushort8*>(r1);
                int up = __shfl_up((int)v[7], 1);
                u16 e = (lane == 0) ? r1[-1] : (u16)up;
                acc[0] += bf2f(e);
                #pragma unroll
                for (int i = 1; i < 8; ++i) acc[i] += bf2f(v[i - 1]);
            }
            if (w + 1 < 64) {   // b=+1: row +LP, elements shifted left
                const u16* r1 = rb + LP;
                ushort8 v = *reinterpret_cast<const ushort8*>(r1);
                int dn = __shfl_down((int)v[0], 1);
                u16 e = (lane == 63) ? r1[8] : (u16)dn;
                #pragma unroll
                for (int i = 0; i < 7; ++i) acc[i] += bf2f(v[i + 1]);
                acc[7] += bf2f(e);
            }
        }
        const float4 rn0 = *reinterpret_cast<const float4*>(rnorm + l8);
        const float4 rn1 = *reinterpret_cast<const float4*>(rnorm + l8 + 4);
        float rn[8] = {rn0.x, rn0.y, rn0.z, rn0.w, rn1.x, rn1.y, rn1.z, rn1.w};
        ushort8 res;
        #pragma unroll
        for (int i = 0; i < 8; ++i) {
            float val = (rn[i] != 0.f) ? acc[i] * rn[i] : -1e4f;
            res[i] = f2h16(val);
            if (rn[i] != 0.f) m = fmaxf(m, val);
        }
        vals16[it] = res;
    }
    // block max
    #pragma unroll
    for (int o = 1; o < 64; o <<= 1) m = fmaxf(m, __shfl_xor(m, o));
    __shared__ float red[4];
    if (lane == 0) red[wvi] = m;
    __syncthreads();
    m = fmaxf(fmaxf(red[0], red[1]), fmaxf(red[2], red[3]));
    __syncthreads();
    // block sum of exp2(val - m), from the fp16-rounded values (matches st2's reads)
    float s = 0.f;
    #pragma unroll
    for (int it = 0; it < 7; ++it) {
        int vg = tid + it * 256;
        if (vg >= LP / 8) continue;
        ushort8 res = vals16[it];
        #pragma unroll
        for (int i = 0; i < 8; ++i) s += __builtin_amdgcn_exp2f(h162f(res[i]) - m);
    }
    #pragma unroll
    for (int o = 1; o < 64; o <<= 1) s += __shfl_xor(s, o);
    if (lane == 0) red[wvi] = s;
    __syncthreads();
    if (tid == 0) {
        float Z = red[0] + red[1] + red[2] + red[3];
        statM[p] = m + __log2f(Z);
    }
    // write scT
    #pragma unroll
    for (int it = 0; it < 7; ++it) {
        int vg = tid + it * 256;
        if (vg >= LP / 8) continue;
        *reinterpret_cast<ushort8*>(out + (size_t)p * LP + (vg << 3)) = vals16[it];
    }
}

// stencil2, aligned loads + shuffles: gT[p][l'] = interior ? sum_taps exp2(v - M'_r) : 0
__global__ __launch_bounds__(256) void d7_st2(const u16* __restrict__ in,
                                              const float* __restrict__ statM,
                                              const float* __restrict__ rnorm,
                                              u16* __restrict__ out) {
    int vg = blockIdx.x * 256 + threadIdx.x;
    if (vg >= LP / 8) return;
    const int lane = threadIdx.x & 63;
    int l8 = vg << 3;
    int p = blockIdx.y;
    int h = p >> 6, w = p & 63;
    int W = d7_scaleW(l8);
    float acc[8] = {0.f, 0.f, 0.f, 0.f, 0.f, 0.f, 0.f, 0.f};
    #pragma unroll
    for (int a = -1; a <= 1; ++a) {
        int ph = h + a;
        if ((unsigned)ph >= 64u) continue;
        const u16* rb = in + (size_t)(p + a * 64) * LP + l8 + a * W;
        {
            float M = statM[p + a * 64];
            ushort8 v = *reinterpret_cast<const ushort8*>(rb);
            #pragma unroll
            for (int i = 0; i < 8; ++i) acc[i] += __builtin_amdgcn_exp2f(h162f(v[i]) - M);
        }
        if (w - 1 >= 0) {
            float M = statM[p + a * 64 - 1];
            const u16* r1 = rb - LP;
            ushort8 v = *reinterpret_cast<const ushort8*>(r1);
            int up = __shfl_up((int)v[7], 1);
            u16 e = (lane == 0) ? r1[-1] : (u16)up;
            acc[0] += __builtin_amdgcn_exp2f(h162f(e) - M);
            #pragma unroll
            for (int i = 1; i < 8; ++i) acc[i] += __builtin_amdgcn_exp2f(h162f(v[i - 1]) - M);
        }
        if (w + 1 < 64) {
            float M = statM[p + a * 64 + 1];
            const u16* r1 = rb + LP;
            ushort8 v = *reinterpret_cast<const ushort8*>(r1);
            int dn = __shfl_down((int)v[0], 1);
            u16 e = (lane == 63) ? r1[8] : (u16)dn;
            #pragma unroll
            for (int i = 0; i < 7; ++i) acc[i] += __builtin_amdgcn_exp2f(h162f(v[i + 1]) - M);
            acc[7] += __builtin_amdgcn_exp2f(h162f(e) - M);
        }
    }
    const float4 rn0 = *reinterpret_cast<const float4*>(rnorm + l8);
    const float4 rn1 = *reinterpret_cast<const float4*>(rnorm + l8 + 4);
    float rn[8] = {rn0.x, rn0.y, rn0.z, rn0.w, rn1.x, rn1.y, rn1.z, rn1.w};
    ushort8 res;
    #pragma unroll
    for (int i = 0; i < 8; ++i)
        res[i] = f2bf((rn[i] != 0.f) ? acc[i] : 0.f);
    *reinterpret_cast<ushort8*>(out + (size_t)p * LP + l8) = res;
}

// ---------------------------------------------------------------------------
extern "C" void kernel_launch(void* const* d_in, const int* in_sizes, int n_in,
                              void* d_out, int out_size, void* d_ws, size_t ws_size,
                              hipStream_t stream) {
    const float* x      = (const float*)d_in[0];
    const float* bb0_w  = (const float*)d_in[1];
    const float* bb0_b  = (const float*)d_in[2];
    const float* bb0_a  = (const float*)d_in[3];
    const float* rb1_w1 = (const float*)d_in[4];
    const float* rb1_b1 = (const float*)d_in[5];
    const float* rb1_w2 = (const float*)d_in[6];
    const float* rb1_b2 = (const float*)d_in[7];
    const float* pamb_w = (const float*)d_in[8];
    const float* pamb_b = (const float*)d_in[9];
    const float* pamb_a = (const float*)d_in[10];
    const float* pam_w  = (const float*)d_in[11];
    const float* pam_b  = (const float*)d_in[12];
    const float* pam_a  = (const float*)d_in[13];
    const float* paa_w  = (const float*)d_in[14];
    const float* paa_b  = (const float*)d_in[15];
    const float* paa_a  = (const float*)d_in[16];
    const float* rb2_w1 = (const float*)d_in[17];
    const float* rb2_b1 = (const float*)d_in[18];
    const float* rb2_w2 = (const float*)d_in[19];
    const float* rb2_b2 = (const float*)d_in[20];
    float* out = (float*)d_out;
    (void)in_sizes; (void)n_in; (void)out_size; (void)ws_size;

    char* wp = (char*)d_ws;
    auto alloc = [&](size_t nbytes) { void* p = wp; wp += (nbytes + 255) & ~(size_t)255; return p; };
    const size_t BIG = 4096ull * LP * 2;             // 113 MB
    char* big1r  = (char*)alloc(BIG + 1024);
    char* big2r  = (char*)alloc(BIG + 1024);
    float* h0f   = (float*)alloc(2ull * 64 * 4096 * 4);
    float* h1f   = (float*)alloc(2ull * 128 * 4096 * 4);
    float* h2f   = (float*)alloc(2ull * 128 * 4096 * 4);
    float* paf   = (float*)alloc(2ull * 128 * 4096 * 4);
    float* tbuf  = (float*)alloc(2ull * 128 * 4096 * 4);
    u16* mbT     = (u16*)alloc(2ull * 4096 * 64 * 2);
    u16* refmT   = (u16*)alloc(2ull * LP * 64 * 2);
    u16* baseA   = (u16*)alloc(2ull * 128 * LP * 2);
    float* s2b   = (float*)alloc(2ull * LP * 4);
    float* rnorm = (float*)alloc(2ull * LP * 4);
    float* statM = (float*)alloc(4096ull * 4);
    u16* W1      = (u16*)alloc(256ull * 128 * 2);
    u16* W2      = (u16*)alloc(256ull * 128 * 2);
    float* b1v   = (float*)alloc(256 * 4);
    float* a1v   = (float*)alloc(256 * 4);
    float* b2v   = (float*)alloc(256 * 4);
    float* a2v   = (float*)alloc(256 * 4);
    u16* A0      = (u16*)alloc(73728ull * 2);
    u16* A1      = (u16*)alloc(147456ull * 2);
    u16* A2      = (u16*)alloc(147456ull * 2);
    u16* A3      = (u16*)alloc(147456ull * 2);
    u16* A4      = (u16*)alloc(147456ull * 2);
    // Views inside the big buffers (lifetime-disjoint phases):
    u16* patT    = (u16*)big1r;
    u16* h2T     = (u16*)big1r;                          // [2][4096][128]
    u16* refbT   = (u16*)(big1r + (4ull << 20));         // [2][7808][128]
    u16* S0T     = (u16*)(big1r + 512);
    u16* gT      = (u16*)(big1r + 512);
    float* parts = (float*)big2r;                        // bf16 split-K partials (all GEMMs)
    u16* cT1     = (u16*)big2r;                          // [2][4096][256]
    u16* cOut1   = (u16*)(big2r + (4ull << 20));         // [2][256][4096]
    u16* cT2     = (u16*)(big2r + (8ull << 20));         // [2][7808][256]
    u16* cOut2   = (u16*)(big2r + (16ull << 20));        // [2][256][7808]
    float* refb  = (float*)(big2r + (26ull << 20));      // [2][level][128][OS^2]
    u16* scT     = (u16*)(big2r + 512);

    const long h2bs = 128L * 4096;
    const long pMN = 128L * 4096;
    const long refbs = 128L * 7786;
    const long mbTbs = 4096L * 64, rmTbs = (long)LP * 64, baBS = 128L * LP;
    const long cT1bs = 4096L * 256, cO1bs = 256L * 4096;
    const long cT2bs = 7808L * 256, cO2bs = 256L * 7808;
    const long rbTbs = 7808L * 128;

    auto conv = [&](const float* src, const u16* W, int Cin, const float* bias,
                    const float* alpha, int act, const float* resid, float* dst) {
        int K = Cin * 9;
        d7_im2col<<<dim3((K + 255) / 256, 4096, 2), 256, 0, stream>>>(src, patT, Cin, (long)Cin * 4096, 4096L * K);
        d7_gemm<<<dim3(32, 6, 2), 256, 0, stream>>>(W, patT, 4096, K, K / 6, 1, 6,
            0, 4096L * K, nullptr, nullptr, 0, nullptr, 0,
            nullptr, 0, nullptr, 0, nullptr, 0, 0, parts, pMN, 1);
        d7_epi<<<dim3(2048, 1, 2), 256, 0, stream>>>(parts, 6, pMN, 6 * pMN,
            bias, alpha, act, resid, h2bs, 1.0f, dst, h2bs, (int)pMN, 1);
    };

    d7_cast<<<dim3(288), 256, 0, stream>>>(bb0_w, A0, 73728);
    d7_cast<<<dim3(576), 256, 0, stream>>>(rb1_w1, A1, 147456);
    d7_cast<<<dim3(576), 256, 0, stream>>>(rb1_w2, A2, 147456);
    d7_cast<<<dim3(576), 256, 0, stream>>>(rb2_w1, A3, 147456);
    d7_cast<<<dim3(576), 256, 0, stream>>>(rb2_w2, A4, 147456);
    d7_wbuild<<<dim3(128), 256, 0, stream>>>(pamb_w, pam_w, paa_w, pamb_b, pam_b, paa_b,
                                             pamb_a, pam_a, paa_a, W1, W2, b1v, a1v, b2v, a2v);

    d7_maxpool<<<dim3(16, 64, 2), 256, 0, stream>>>(x, h0f);
    conv(h0f, A0, 64, bb0_b, bb0_a, 1, nullptr, h1f);
    conv(h1f, A1, 128, rb1_b1, nullptr, 2, nullptr, tbuf);
    conv(tbuf, A2, 128, rb1_b2, nullptr, 0, h1f, h2f);

    d7_resize<57><<<dim3(13, 128, 2), 256, 0, stream>>>(h2f, refb, refbs);
    d7_resize<51><<<dim3(11, 128, 2), 256, 0, stream>>>(h2f, refb + 3249L * 128, refbs);
    d7_resize<44><<<dim3(8, 128, 2), 256, 0, stream>>>(h2f, refb + 5850L * 128, refbs);

    // p-major bf16 operands for the fused 1x1-conv GEMMs (per-level transpose)
    hipMemsetAsync(refbT, 0, 2ull * rbTbs * 2, stream);
    d7_t32<<<dim3(128, 4, 2), 256, 0, stream>>>(h2f, h2bs, 4096, h2T, 4096L * 128);
    d7_t32<<<dim3(102, 4, 2), 256, 0, stream>>>(refb, refbs, 3249, refbT, rbTbs);
    d7_t32<<<dim3(82, 4, 2), 256, 0, stream>>>(refb + 3249L * 128, refbs, 2601, refbT + 3249L * 128, rbTbs);
    d7_t32<<<dim3(61, 4, 2), 256, 0, stream>>>(refb + 5850L * 128, refbs, 1936, refbT + 5850L * 128, rbTbs);

    // all 1x1 convs as two GEMMs
    d7_gemm<<<dim3(32, 2, 2), 256, 0, stream>>>(W1, h2T, 4096, 128, 128, 2, 1,
        0, 4096L * 128, b1v, a1v, 3, nullptr, 0,
        nullptr, 0, cOut1, cO1bs, cT1, 256, cT1bs, nullptr, 0, 0);
    d7_gemm<<<dim3(61, 2, 2), 256, 0, stream>>>(W2, refbT, 7808, 128, 128, 2, 1,
        0, rbTbs, b2v, a2v, 3, nullptr, 0,
        nullptr, 0, cOut2, cO2bs, cT2, 256, cT2bs, nullptr, 0, 0);

    // scatter into padded attention layouts (+ fused s2 for refmT)
    hipMemsetAsync(refmT, 0, 2ull * LP * 64 * 2, stream);
    hipMemsetAsync(baseA, 0, 2ull * 128 * LP * 2, stream);
    hipMemsetAsync(s2b, 0, 2ull * LP * 4, stream);
    d7_scK<<<dim3(128, 1, 2), 256, 0, stream>>>(cT1, cT1bs, 256, 0, 0, 4096, 64, 64, -65, mbT, mbTbs, nullptr);
    d7_scK<<<dim3(128, 1, 2), 256, 0, stream>>>(cT1, cT1bs, 256, 64, 0, 4096, 64, 72, 0, refmT, rmTbs, s2b);
    d7_scK<<<dim3(102, 1, 2), 256, 0, stream>>>(cT2, cT2bs, 256, 0, 0, 3249, 57, 64, 4752, refmT, rmTbs, s2b);
    d7_scK<<<dim3(82, 1, 2), 256, 0, stream>>>(cT2, cT2bs, 256, 0, 3249, 2601, 51, 56, 8528, refmT, rmTbs, s2b);
    d7_scK<<<dim3(61, 1, 2), 256, 0, stream>>>(cT2, cT2bs, 256, 0, 5850, 1936, 44, 48, 11496, refmT, rmTbs, s2b);
    d7_scR<<<dim3(16, 128, 2), 256, 0, stream>>>(cOut1, cO1bs, 4096, 128, 0, 4096, 64, 72, 0, baseA, baBS);
    d7_scR<<<dim3(13, 128, 2), 256, 0, stream>>>(cOut2, cO2bs, 7808, 64, 0, 3249, 57, 64, 4752, baseA, baBS);
    d7_scR<<<dim3(11, 128, 2), 256, 0, stream>>>(cOut2, cO2bs, 7808, 64, 3249, 2601, 51, 56, 8528, baseA, baBS);
    d7_scR<<<dim3(8, 128, 2), 256, 0, stream>>>(cOut2, cO2bs, 7808, 64, 5850, 1936, 44, 48, 11496, baseA, baBS);

    d7_rnormk<<<dim3(54, 1, 2), 256, 0, stream>>>(s2b, rnorm);

    for (int b = 0; b < 2; ++b) {
        // S0T[p][l'] via transposed 8B stores: A=refmT (M=LP), B=mbT (N=4096)
        d7_gemm<<<dim3(32, 108, 1), 256, 0, stream>>>(refmT + b * rmTbs, mbT + b * mbTbs,
            4096, 64, 64, 108, 1, 0, 0, nullptr, nullptr, 0, nullptr, 0,
            nullptr, 0, nullptr, 0, S0T, LP, 0, nullptr, 0, 0);
        d7_st1f<<<dim3(4096), 256, 0, stream>>>(S0T, scT, rnorm + (size_t)b * LP, statM);
        d7_st2<<<dim3(7, 4096), 256, 0, stream>>>(scT, statM, rnorm + (size_t)b * LP, gT);
        // out_pa = h2f + 0.25 * baseA · gT^T  (split-K = 12, bf16 partials)
        d7_gemm<<<dim3(32, 12, 1), 256, 0, stream>>>(baseA + b * baBS, gT,
            4096, LP, LP / 12, 1, 12, 0, 0, nullptr, nullptr, 0, nullptr, 0,
            nullptr, 0, nullptr, 0, nullptr, 0, 0, parts, pMN, 1);
        d7_epi<<<dim3(2048, 1, 1), 256, 0, stream>>>(parts, 12, pMN, 0,
            nullptr, nullptr, 0, h2f + b * h2bs, 0, 0.25f, paf + b * h2bs, 0, (int)pMN, 1);
    }

    conv(paf, A3, 128, rb2_b1, nullptr, 2, nullptr, tbuf);
    conv(tbuf, A4, 128, rb2_b2, nullptr, 0, paf, out);
}

// Round 9
// 1006.181 us; speedup vs baseline: 1.0283x; 1.0283x over previous
//
#include <hip/hip_runtime.h>

typedef unsigned short u16;
typedef __attribute__((ext_vector_type(8))) __bf16 bf16x8;
typedef __attribute__((ext_vector_type(8))) unsigned short ushort8;
typedef __attribute__((ext_vector_type(4))) float f32x4;

__device__ __forceinline__ float bf2f(u16 u) { return __uint_as_float(((unsigned)u) << 16); }
__device__ __forceinline__ u16 f2bf(float f) {
    unsigned x = __float_as_uint(f);
    x += 0x7fffu + ((x >> 16) & 1u);
    return (u16)(x >> 16);
}
__device__ __forceinline__ u16 f2h16(float f) {
    _Float16 h = (_Float16)f; u16 r; __builtin_memcpy(&r, &h, 2); return r;
}
__device__ __forceinline__ float h162f(u16 u) {
    _Float16 h; __builtin_memcpy(&h, &u, 2); return (float)h;
}

// Padded l-space: per-scale (HS+2) rows x W' cols with zero border, W' mult of 8.
// scale0: HS=64 W=72 off=0      (66*72=4752)
// scale1: HS=57 W=64 off=4752   (59*64=3776)
// scale2: HS=51 W=56 off=8528   (53*56=2968)
// scale3: HS=44 W=48 off=11496  (46*48=2208) -> 13704, dead zone to LP=13824
#define LP 13824

// ---------------------------------------------------------------------------
// GEMM: C[M,N] = A[M,K] * B[N,K]^T  (bf16 in, fp32 acc), 128x128 tile, BK=32.
// ---------------------------------------------------------------------------
__global__ __launch_bounds__(256) void d7_gemm(
    const u16* __restrict__ A, const u16* __restrict__ B,
    int N, int K, int kLen, int mTiles, int S,
    long aBS, long bBS,
    const float* __restrict__ bias, const float* __restrict__ alpha, int act,
    const float* __restrict__ resid, long residBS,
    float* __restrict__ outF, long oFBS,
    u16* __restrict__ outB, long oBBS,
    u16* __restrict__ outT, int ldT, long oTBS,
    float* __restrict__ outP, long pMN, int pBf)
{
    __shared__ u16 As[128 * 40];
    __shared__ u16 Bs[128 * 40];

    const int tid = threadIdx.x;
    const int wv = tid >> 6, lane = tid & 63;
    const int wm = wv >> 1, wn = wv & 1;
    const int bn = blockIdx.x;
    const int bm = blockIdx.y % mTiles;
    const int ks = blockIdx.y / mTiles;
    const int z  = blockIdx.z;
    const int kStart = ks * kLen;

    const int srow = tid >> 1;
    const int soff = (tid & 1) * 16;
    const u16* gA = A + z * aBS + (size_t)(bm * 128 + srow) * K + kStart + soff;
    const u16* gB = B + z * bBS + (size_t)(bn * 128 + srow) * K + kStart + soff;
    u16* lA = &As[srow * 40 + soff];
    u16* lB = &Bs[srow * 40 + soff];

    f32x4 acc[4][4] = {};

    for (int k0 = 0; k0 < kLen; k0 += 32) {
        __syncthreads();
        ((uint4*)lA)[0] = ((const uint4*)gA)[0];
        ((uint4*)lA)[1] = ((const uint4*)gA)[1];
        ((uint4*)lB)[0] = ((const uint4*)gB)[0];
        ((uint4*)lB)[1] = ((const uint4*)gB)[1];
        gA += 32; gB += 32;
        __syncthreads();

        bf16x8 a[4], b[4];
        #pragma unroll
        for (int mt = 0; mt < 4; ++mt)
            a[mt] = *reinterpret_cast<const bf16x8*>(&As[(wm * 64 + mt * 16 + (lane & 15)) * 40 + (lane >> 4) * 8]);
        #pragma unroll
        for (int nt = 0; nt < 4; ++nt)
            b[nt] = *reinterpret_cast<const bf16x8*>(&Bs[(wn * 64 + nt * 16 + (lane & 15)) * 40 + (lane >> 4) * 8]);
        #pragma unroll
        for (int mt = 0; mt < 4; ++mt)
            #pragma unroll
            for (int nt = 0; nt < 4; ++nt)
                acc[mt][nt] = __builtin_amdgcn_mfma_f32_16x16x32_bf16(a[mt], b[nt], acc[mt][nt], 0, 0, 0);
    }

    if (outP) {
        const size_t pbase = ((size_t)z * S + ks) * pMN;
        #pragma unroll
        for (int mt = 0; mt < 4; ++mt) {
            const int mg = bm * 128 + wm * 64 + mt * 16 + ((lane >> 4) << 2);
            #pragma unroll
            for (int nt = 0; nt < 4; ++nt) {
                const int ng = bn * 128 + wn * 64 + nt * 16 + (lane & 15);
                if (pBf) {
                    u16* pp = (u16*)outP + pbase;
                    #pragma unroll
                    for (int r = 0; r < 4; ++r)
                        pp[(size_t)(mg + r) * N + ng] = f2bf(acc[mt][nt][r]);
                } else {
                    float* pp = outP + pbase;
                    #pragma unroll
                    for (int r = 0; r < 4; ++r)
                        pp[(size_t)(mg + r) * N + ng] = acc[mt][nt][r];
                }
            }
        }
        return;
    }

    const float avalS = (act == 1) ? alpha[0] : 0.0f;
    #pragma unroll
    for (int mt = 0; mt < 4; ++mt) {
        const int mg = bm * 128 + wm * 64 + mt * 16 + ((lane >> 4) << 2);
        float bv[4] = {0.f, 0.f, 0.f, 0.f}, av[4];
        if (bias) {
            #pragma unroll
            for (int r = 0; r < 4; ++r) bv[r] = bias[mg + r];
        }
        if (act == 3) {
            #pragma unroll
            for (int r = 0; r < 4; ++r) av[r] = alpha[mg + r];
        }
        #pragma unroll
        for (int nt = 0; nt < 4; ++nt) {
            const int ng = bn * 128 + wn * 64 + nt * 16 + (lane & 15);
            float v[4];
            #pragma unroll
            for (int r = 0; r < 4; ++r) {
                float t = acc[mt][nt][r] + bv[r];
                if (act == 1) t = (t >= 0.f) ? t : avalS * t;
                else if (act == 2) t = fmaxf(t, 0.f);
                else if (act == 3) t = (t >= 0.f) ? t : av[r] * t;
                if (resid) t += resid[z * residBS + (size_t)(mg + r) * N + ng];
                v[r] = t;
            }
            if (outF) {
                #pragma unroll
                for (int r = 0; r < 4; ++r) outF[z * oFBS + (size_t)(mg + r) * N + ng] = v[r];
            }
            if (outB) {
                #pragma unroll
                for (int r = 0; r < 4; ++r) outB[z * oBBS + (size_t)(mg + r) * N + ng] = f2bf(v[r]);
            }
            if (outT) {
                unsigned long long pk = (unsigned long long)f2bf(v[0])
                    | ((unsigned long long)f2bf(v[1]) << 16)
                    | ((unsigned long long)f2bf(v[2]) << 32)
                    | ((unsigned long long)f2bf(v[3]) << 48);
                *reinterpret_cast<unsigned long long*>(outT + z * oTBS + (size_t)ng * ldT + mg) = pk;
            }
        }
    }
}

// split-K reduce + bias/act/resid epilogue; N fixed 4096 (m = i>>12)
__global__ __launch_bounds__(256) void d7_epi(
    const void* __restrict__ parts, int S, long sStride, long bStride,
    const float* __restrict__ bias, const float* __restrict__ alpha, int act,
    const float* __restrict__ resid, long residBS, float scale,
    float* __restrict__ out, long outBS, int total, int pBf)
{
    int i = blockIdx.x * 256 + threadIdx.x;
    if (i >= total) return;
    int b = blockIdx.z;
    float s = 0.f;
    if (pBf) {
        const u16* p = (const u16*)parts + b * bStride + i;
        for (int t = 0; t < S; ++t) s += bf2f(p[(size_t)t * sStride]);
    } else {
        const float* p = (const float*)parts + b * bStride + i;
        for (int t = 0; t < S; ++t) s += p[(size_t)t * sStride];
    }
    s *= scale;
    if (bias) s += bias[i >> 12];
    if (act == 1) { float a = alpha[0]; s = (s >= 0.f) ? s : a * s; }
    else if (act == 2) s = fmaxf(s, 0.f);
    if (resid) s += resid[b * residBS + i];
    out[b * outBS + i] = s;
}

// ---------------------------------------------------------------------------
__global__ __launch_bounds__(256) void d7_cast(const float* __restrict__ src, u16* __restrict__ dst, int n) {
    int i = blockIdx.x * 256 + threadIdx.x;
    if (i < n) dst[i] = f2bf(src[i]);
}

__global__ __launch_bounds__(256) void d7_wbuild(
    const float* __restrict__ pamb_w, const float* __restrict__ pam_w, const float* __restrict__ paa_w,
    const float* __restrict__ pamb_b, const float* __restrict__ pam_b, const float* __restrict__ paa_b,
    const float* __restrict__ pamb_a, const float* __restrict__ pam_a, const float* __restrict__ paa_a,
    u16* __restrict__ W1, u16* __restrict__ W2,
    float* __restrict__ b1, float* __restrict__ a1,
    float* __restrict__ b2, float* __restrict__ a2)
{
    int i = blockIdx.x * 256 + threadIdx.x;
    if (i < 256 * 128) {
        int r = i >> 7, c = i & 127;
        float w1 = (r < 64) ? pamb_w[r * 128 + c] : (r < 128) ? pam_w[(r - 64) * 128 + c] : paa_w[(r - 128) * 128 + c];
        W1[i] = f2bf(w1);
        float w2 = (r < 64) ? pam_w[r * 128 + c] : (r < 192) ? paa_w[(r - 64) * 128 + c] : 0.f;
        W2[i] = f2bf(w2);
    }
    if (i < 256) {
        int r = i;
        b1[r] = (r < 64) ? pamb_b[r] : (r < 128) ? pam_b[r - 64] : paa_b[r - 128];
        a1[r] = (r < 64) ? pamb_a[0] : (r < 128) ? pam_a[0] : paa_a[0];
        b2[r] = (r < 64) ? pam_b[r] : (r < 192) ? paa_b[r - 64] : 0.f;
        a2[r] = (r < 64) ? pam_a[0] : (r < 192) ? paa_a[0] : 0.f;
    }
}

__global__ __launch_bounds__(256) void d7_maxpool(const float* __restrict__ x, float* __restrict__ out) {
    int p = blockIdx.x * 256 + threadIdx.x;
    int c = blockIdx.y, b = blockIdx.z;
    int oh = p >> 6, ow = p & 63;
    const float* ip = x + ((size_t)b * 64 + c) * 16384;
    float v0 = ip[(2 * oh) * 128 + 2 * ow];
    float v1 = ip[(2 * oh) * 128 + 2 * ow + 1];
    float v2 = ip[(2 * oh + 1) * 128 + 2 * ow];
    float v3 = ip[(2 * oh + 1) * 128 + 2 * ow + 1];
    out[((size_t)b * 64 + c) * 4096 + p] = fmaxf(fmaxf(v0, v1), fmaxf(v2, v3));
}

__global__ __launch_bounds__(256) void d7_im2col(const float* __restrict__ img, u16* __restrict__ patT,
                                                 int Cin, long inBS, long outBS) {
    int K = Cin * 9;
    int k = blockIdx.x * 256 + threadIdx.x;
    if (k >= K) return;
    int p = blockIdx.y, b = blockIdx.z;
    int c = k / 9, k9 = k - c * 9;
    int h = p >> 6, w = p & 63;
    int y = h + k9 / 3 - 1, x = w + (k9 % 3) - 1;
    const float* ip = img + b * inBS;
    float v = (y >= 0 && y < 64 && x >= 0 && x < 64) ? ip[(size_t)c * 4096 + y * 64 + x] : 0.f;
    patT[b * outBS + (size_t)p * K + k] = f2bf(v);
}

// transpose-cast: in fp32 [128][P] -> out bf16 [p][128]
__global__ __launch_bounds__(256) void d7_t32(const float* __restrict__ in, long inBS, int P,
                                              u16* __restrict__ out, long outBS) {
    __shared__ float tile[32][33];
    int p0 = blockIdx.x * 32, c0 = blockIdx.y * 32, b = blockIdx.z;
    int tx = threadIdx.x & 31, ty = threadIdx.x >> 5;
    const float* ip = in + b * inBS;
    #pragma unroll
    for (int i = 0; i < 32; i += 8) {
        int c = c0 + ty + i, p = p0 + tx;
        tile[ty + i][tx] = (p < P) ? ip[(size_t)c * P + p] : 0.f;
    }
    __syncthreads();
    u16* op = out + b * outBS;
    #pragma unroll
    for (int i = 0; i < 32; i += 8) {
        int p = p0 + ty + i, c = c0 + tx;
        if (p < P) op[(size_t)p * 128 + c] = f2bf(tile[tx][ty + i]);
    }
}

// scatter K-major 64-wide rows (+ optional fused s2)
__global__ __launch_bounds__(256) void d7_scK(const u16* __restrict__ cT, long cBS, int ldC, int colBase,
                                              int pOff, int P, int HS, int Wp, int off,
                                              u16* __restrict__ dst, long dBS,
                                              float* __restrict__ s2out) {
    int t = blockIdx.x * 256 + threadIdx.x;
    int p = t >> 3, cg = t & 7;
    if (p >= P) return;
    int b = blockIdx.z;
    ushort8 v = *reinterpret_cast<const ushort8*>(cT + b * cBS + (size_t)(pOff + p) * ldC + colBase + cg * 8);
    int h = p / HS, w = p - h * HS;
    int lp = off + (h + 1) * Wp + w + 1;
    *reinterpret_cast<ushort8*>(dst + b * dBS + (size_t)lp * 64 + cg * 8) = v;
    if (s2out) {
        float ss = 0.f;
        #pragma unroll
        for (int i = 0; i < 8; ++i) { float f = bf2f(v[i]); ss += f * f; }
        ss += __shfl_xor(ss, 1);
        ss += __shfl_xor(ss, 2);
        ss += __shfl_xor(ss, 4);
        if (cg == 0) s2out[(size_t)b * LP + lp] = ss;
    }
}

__global__ __launch_bounds__(256) void d7_scR(const u16* __restrict__ cO, long cBS, int ldC, int rowBase,
                                              int pOff, int P, int HS, int Wp, int off,
                                              u16* __restrict__ dst, long dBS) {
    int p = blockIdx.x * 256 + threadIdx.x;
    if (p >= P) return;
    int co = blockIdx.y, b = blockIdx.z;
    u16 v = cO[b * cBS + (size_t)(rowBase + co) * ldC + pOff + p];
    int h = p / HS, w = p - h * HS;
    int lp = off + (h + 1) * Wp + w + 1;
    dst[b * dBS + (size_t)co * LP + lp] = v;
}

// jax.image.resize bilinear antialias, 64 -> OS
template <int OS>
__device__ __forceinline__ void d7_taps(int o, int& i0, float w3[3]) {
    const float inv = 64.0f / OS;
    float s = (o + 0.5f) * inv - 0.5f;
    i0 = (int)ceilf(s - inv);
    float wsum = 0.f;
    #pragma unroll
    for (int t = 0; t < 3; ++t) {
        int y = i0 + t;
        float wt = 1.0f - fabsf((float)y - s) / inv;
        wt = (wt > 0.f && y >= 0 && y < 64) ? wt : 0.f;
        w3[t] = wt; wsum += wt;
    }
    float r = 1.0f / wsum;
    w3[0] *= r; w3[1] *= r; w3[2] *= r;
}

template <int OS>
__global__ __launch_bounds__(256) void d7_resize(const float* __restrict__ in, float* __restrict__ out, long out_bs) {
    int p = blockIdx.x * 256 + threadIdx.x;
    if (p >= OS * OS) return;
    int c = blockIdx.y, b = blockIdx.z;
    int oh = p / OS, ow = p - oh * OS;
    const float* img = in + ((size_t)b * 128 + c) * 4096;
    int y0, x0; float wy[3], wx[3];
    d7_taps<OS>(oh, y0, wy);
    d7_taps<OS>(ow, x0, wx);
    float sum = 0.f;
    #pragma unroll
    for (int iy = 0; iy < 3; ++iy) {
        if (wy[iy] <= 0.f) continue;
        float rs = 0.f;
        #pragma unroll
        for (int ix = 0; ix < 3; ++ix) {
            if (wx[ix] <= 0.f) continue;
            rs += wx[ix] * img[(y0 + iy) * 64 + (x0 + ix)];
        }
        sum += wy[iy] * rs;
    }
    out[(size_t)b * out_bs + (size_t)c * OS * OS + p] = sum;
}

__device__ __forceinline__ int d7_scaleW(int l) {
    return (l < 4752) ? 72 : (l < 8528) ? 64 : (l < 11496) ? 56 : 48;
}

// rnorm[l'] = interior ? (10*log2e)/max(sqrt(9-tap sum of s2),1e-4) : 0
__global__ __launch_bounds__(256) void d7_rnormk(const float* __restrict__ s2, float* __restrict__ rnorm) {
    int l = blockIdx.x * 256 + threadIdx.x;
    if (l >= LP) return;
    int zb = blockIdx.z;
    int off, W, HS;
    if (l < 4752)       { off = 0;     W = 72; HS = 64; }
    else if (l < 8528)  { off = 4752;  W = 64; HS = 57; }
    else if (l < 11496) { off = 8528;  W = 56; HS = 51; }
    else                { off = 11496; W = 48; HS = 44; }
    int li = l - off, y = li / W, x = li - y * W;
    float v = 0.f;
    if (y >= 1 && y <= HS && x >= 1 && x <= HS) {
        const float* s = s2 + (size_t)zb * LP;
        float a = 0.f;
        #pragma unroll
        for (int dy = -1; dy <= 1; ++dy)
            #pragma unroll
            for (int dx = -1; dx <= 1; ++dx)
                a += s[l + dy * W + dx];
        v = 14.426950408889634f / fmaxf(sqrtf(a), 1e-4f);
    }
    rnorm[(size_t)zb * LP + l] = v;
}

// stencil1 (separate, high-occupancy): aligned 16B loads + lane shuffles for +/-1.
// scT fp16 log2-domain (pads -1e4).
__global__ __launch_bounds__(256) void d7_st1(const u16* __restrict__ in, u16* __restrict__ out,
                                              const float* __restrict__ rnorm) {
    int vg = blockIdx.x * 256 + threadIdx.x;
    if (vg >= LP / 8) return;
    const int lane = threadIdx.x & 63;
    int l8 = vg << 3;
    int p = blockIdx.y;
    int h = p >> 6, w = p & 63;
    int W = d7_scaleW(l8);
    float acc[8] = {0.f, 0.f, 0.f, 0.f, 0.f, 0.f, 0.f, 0.f};
    #pragma unroll
    for (int a = -1; a <= 1; ++a) {
        int ph = h + a;
        if ((unsigned)ph >= 64u) continue;
        const u16* rb = in + (size_t)(p + a * 64) * LP + l8 + a * W;   // aligned base (b=0 row)
        {
            ushort8 v = *reinterpret_cast<const ushort8*>(rb);
            #pragma unroll
            for (int i = 0; i < 8; ++i) acc[i] += bf2f(v[i]);
        }
        if (w - 1 >= 0) {       // b=-1: row -LP, elements shifted right by 1
            const u16* r1 = rb - LP;
            ushort8 v = *reinterpret_cast<const ushort8*>(r1);
            int up = __shfl_up((int)v[7], 1);
            u16 e = (lane == 0) ? r1[-1] : (u16)up;
            acc[0] += bf2f(e);
            #pragma unroll
            for (int i = 1; i < 8; ++i) acc[i] += bf2f(v[i - 1]);
        }
        if (w + 1 < 64) {       // b=+1: row +LP, elements shifted left by 1
            const u16* r1 = rb + LP;
            ushort8 v = *reinterpret_cast<const ushort8*>(r1);
            int dn = __shfl_down((int)v[0], 1);
            u16 e = (lane == 63) ? r1[8] : (u16)dn;
            #pragma unroll
            for (int i = 0; i < 7; ++i) acc[i] += bf2f(v[i + 1]);
            acc[7] += bf2f(e);
        }
    }
    const float4 rn0 = *reinterpret_cast<const float4*>(rnorm + l8);
    const float4 rn1 = *reinterpret_cast<const float4*>(rnorm + l8 + 4);
    float rn[8] = {rn0.x, rn0.y, rn0.z, rn0.w, rn1.x, rn1.y, rn1.z, rn1.w};
    ushort8 res;
    #pragma unroll
    for (int i = 0; i < 8; ++i)
        res[i] = f2h16((rn[i] != 0.f) ? acc[i] * rn[i] : -1e4f);
    *reinterpret_cast<ushort8*>(out + (size_t)p * LP + l8) = res;
}

// per-row softmax stat (log2 domain): statM[p] = m + log2(Z), Z = sum exp2(v-m)
__global__ __launch_bounds__(256) void d7_stats(const u16* __restrict__ sc, float* __restrict__ statM) {
    int p = blockIdx.x, tid = threadIdx.x, wv = tid >> 6, lane = tid & 63;
    const u16* row = sc + (size_t)p * LP;
    float m = -3e38f;
    #pragma unroll
    for (int it = 0; it < 7; ++it) {
        int vg = tid + it * 256;
        if (vg < LP / 8) {
            ushort8 v = *reinterpret_cast<const ushort8*>(row + vg * 8);
            #pragma unroll
            for (int i = 0; i < 8; ++i) m = fmaxf(m, h162f(v[i]));
        }
    }
    #pragma unroll
    for (int o = 1; o < 64; o <<= 1) m = fmaxf(m, __shfl_xor(m, o));
    __shared__ float red[4];
    if (lane == 0) red[wv] = m;
    __syncthreads();
    m = fmaxf(fmaxf(red[0], red[1]), fmaxf(red[2], red[3]));
    __syncthreads();
    float s = 0.f;
    #pragma unroll
    for (int it = 0; it < 7; ++it) {
        int vg = tid + it * 256;
        if (vg < LP / 8) {
            ushort8 v = *reinterpret_cast<const ushort8*>(row + vg * 8);
            #pragma unroll
            for (int i = 0; i < 8; ++i) s += __builtin_amdgcn_exp2f(h162f(v[i]) - m);
        }
    }
    #pragma unroll
    for (int o = 1; o < 64; o <<= 1) s += __shfl_xor(s, o);
    if (lane == 0) red[wv] = s;
    __syncthreads();
    if (tid == 0) {
        float Z = red[0] + red[1] + red[2] + red[3];
        statM[p] = m + __log2f(Z);
    }
}

// stencil2, aligned loads + shuffles: gT[p][l'] = interior ? sum_taps exp2(v - M'_r) : 0
__global__ __launch_bounds__(256) void d7_st2(const u16* __restrict__ in,
                                              const float* __restrict__ statM,
                                              const float* __restrict__ rnorm,
                                              u16* __restrict__ out) {
    int vg = blockIdx.x * 256 + threadIdx.x;
    if (vg >= LP / 8) return;
    const int lane = threadIdx.x & 63;
    int l8 = vg << 3;
    int p = blockIdx.y;
    int h = p >> 6, w = p & 63;
    int W = d7_scaleW(l8);
    float acc[8] = {0.f, 0.f, 0.f, 0.f, 0.f, 0.f, 0.f, 0.f};
    #pragma unroll
    for (int a = -1; a <= 1; ++a) {
        int ph = h + a;
        if ((unsigned)ph >= 64u) continue;
        const u16* rb = in + (size_t)(p + a * 64) * LP + l8 + a * W;
        {
            float M = statM[p + a * 64];
            ushort8 v = *reinterpret_cast<const ushort8*>(rb);
            #pragma unroll
            for (int i = 0; i < 8; ++i) acc[i] += __builtin_amdgcn_exp2f(h162f(v[i]) - M);
        }
        if (w - 1 >= 0) {
            float M = statM[p + a * 64 - 1];
            const u16* r1 = rb - LP;
            ushort8 v = *reinterpret_cast<const ushort8*>(r1);
            int up = __shfl_up((int)v[7], 1);
            u16 e = (lane == 0) ? r1[-1] : (u16)up;
            acc[0] += __builtin_amdgcn_exp2f(h162f(e) - M);
            #pragma unroll
            for (int i = 1; i < 8; ++i) acc[i] += __builtin_amdgcn_exp2f(h162f(v[i - 1]) - M);
        }
        if (w + 1 < 64) {
            float M = statM[p + a * 64 + 1];
            const u16* r1 = rb + LP;
            ushort8 v = *reinterpret_cast<const ushort8*>(r1);
            int dn = __shfl_down((int)v[0], 1);
            u16 e = (lane == 63) ? r1[8] : (u16)dn;
            #pragma unroll
            for (int i = 0; i < 7; ++i) acc[i] += __builtin_amdgcn_exp2f(h162f(v[i + 1]) - M);
            acc[7] += __builtin_amdgcn_exp2f(h162f(e) - M);
        }
    }
    const float4 rn0 = *reinterpret_cast<const float4*>(rnorm + l8);
    const float4 rn1 = *reinterpret_cast<const float4*>(rnorm + l8 + 4);
    float rn[8] = {rn0.x, rn0.y, rn0.z, rn0.w, rn1.x, rn1.y, rn1.z, rn1.w};
    ushort8 res;
    #pragma unroll
    for (int i = 0; i < 8; ++i)
        res[i] = f2bf((rn[i] != 0.f) ? acc[i] : 0.f);
    *reinterpret_cast<ushort8*>(out + (size_t)p * LP + l8) = res;
}

// ---------------------------------------------------------------------------
extern "C" void kernel_launch(void* const* d_in, const int* in_sizes, int n_in,
                              void* d_out, int out_size, void* d_ws, size_t ws_size,
                              hipStream_t stream) {
    const float* x      = (const float*)d_in[0];
    const float* bb0_w  = (const float*)d_in[1];
    const float* bb0_b  = (const float*)d_in[2];
    const float* bb0_a  = (const float*)d_in[3];
    const float* rb1_w1 = (const float*)d_in[4];
    const float* rb1_b1 = (const float*)d_in[5];
    const float* rb1_w2 = (const float*)d_in[6];
    const float* rb1_b2 = (const float*)d_in[7];
    const float* pamb_w = (const float*)d_in[8];
    const float* pamb_b = (const float*)d_in[9];
    const float* pamb_a = (const float*)d_in[10];
    const float* pam_w  = (const float*)d_in[11];
    const float* pam_b  = (const float*)d_in[12];
    const float* pam_a  = (const float*)d_in[13];
    const float* paa_w  = (const float*)d_in[14];
    const float* paa_b  = (const float*)d_in[15];
    const float* paa_a  = (const float*)d_in[16];
    const float* rb2_w1 = (const float*)d_in[17];
    const float* rb2_b1 = (const float*)d_in[18];
    const float* rb2_w2 = (const float*)d_in[19];
    const float* rb2_b2 = (const float*)d_in[20];
    float* out = (float*)d_out;
    (void)in_sizes; (void)n_in; (void)out_size; (void)ws_size;

    char* wp = (char*)d_ws;
    auto alloc = [&](size_t nbytes) { void* p = wp; wp += (nbytes + 255) & ~(size_t)255; return p; };
    const size_t BIG = 4096ull * LP * 2;             // 113 MB
    char* big1r  = (char*)alloc(BIG + 1024);
    char* big2r  = (char*)alloc(BIG + 1024);
    float* h0f   = (float*)alloc(2ull * 64 * 4096 * 4);
    float* h1f   = (float*)alloc(2ull * 128 * 4096 * 4);
    float* h2f   = (float*)alloc(2ull * 128 * 4096 * 4);
    float* paf   = (float*)alloc(2ull * 128 * 4096 * 4);
    float* tbuf  = (float*)alloc(2ull * 128 * 4096 * 4);
    u16* mbT     = (u16*)alloc(2ull * 4096 * 64 * 2);
    u16* refmT   = (u16*)alloc(2ull * LP * 64 * 2);
    u16* baseA   = (u16*)alloc(2ull * 128 * LP * 2);
    float* s2b   = (float*)alloc(2ull * LP * 4);
    float* rnorm = (float*)alloc(2ull * LP * 4);
    float* statM = (float*)alloc(4096ull * 4);
    u16* W1      = (u16*)alloc(256ull * 128 * 2);
    u16* W2      = (u16*)alloc(256ull * 128 * 2);
    float* b1v   = (float*)alloc(256 * 4);
    float* a1v   = (float*)alloc(256 * 4);
    float* b2v   = (float*)alloc(256 * 4);
    float* a2v   = (float*)alloc(256 * 4);
    u16* A0      = (u16*)alloc(73728ull * 2);
    u16* A1      = (u16*)alloc(147456ull * 2);
    u16* A2      = (u16*)alloc(147456ull * 2);
    u16* A3      = (u16*)alloc(147456ull * 2);
    u16* A4      = (u16*)alloc(147456ull * 2);
    // Views inside the big buffers (lifetime-disjoint phases):
    u16* patT    = (u16*)big1r;
    u16* h2T     = (u16*)big1r;                          // [2][4096][128]
    u16* refbT   = (u16*)(big1r + (4ull << 20));         // [2][7808][128]
    u16* S0T     = (u16*)(big1r + 512);
    u16* gT      = (u16*)(big1r + 512);
    float* parts = (float*)big2r;                        // bf16 split-K partials
    u16* cT1     = (u16*)big2r;                          // [2][4096][256]
    u16* cOut1   = (u16*)(big2r + (4ull << 20));         // [2][256][4096]
    u16* cT2     = (u16*)(big2r + (8ull << 20));         // [2][7808][256]
    u16* cOut2   = (u16*)(big2r + (16ull << 20));        // [2][256][7808]
    float* refb  = (float*)(big2r + (26ull << 20));      // [2][level][128][OS^2]
    u16* scT     = (u16*)(big2r + 512);

    const long h2bs = 128L * 4096;
    const long pMN = 128L * 4096;
    const long refbs = 128L * 7786;
    const long mbTbs = 4096L * 64, rmTbs = (long)LP * 64, baBS = 128L * LP;
    const long cT1bs = 4096L * 256, cO1bs = 256L * 4096;
    const long cT2bs = 7808L * 256, cO2bs = 256L * 7808;
    const long rbTbs = 7808L * 128;

    auto conv = [&](const float* src, const u16* W, int Cin, const float* bias,
                    const float* alpha, int act, const float* resid, float* dst) {
        int K = Cin * 9;
        d7_im2col<<<dim3((K + 255) / 256, 4096, 2), 256, 0, stream>>>(src, patT, Cin, (long)Cin * 4096, 4096L * K);
        d7_gemm<<<dim3(32, 6, 2), 256, 0, stream>>>(W, patT, 4096, K, K / 6, 1, 6,
            0, 4096L * K, nullptr, nullptr, 0, nullptr, 0,
            nullptr, 0, nullptr, 0, nullptr, 0, 0, parts, pMN, 1);
        d7_epi<<<dim3(2048, 1, 2), 256, 0, stream>>>(parts, 6, pMN, 6 * pMN,
            bias, alpha, act, resid, h2bs, 1.0f, dst, h2bs, (int)pMN, 1);
    };

    d7_cast<<<dim3(288), 256, 0, stream>>>(bb0_w, A0, 73728);
    d7_cast<<<dim3(576), 256, 0, stream>>>(rb1_w1, A1, 147456);
    d7_cast<<<dim3(576), 256, 0, stream>>>(rb1_w2, A2, 147456);
    d7_cast<<<dim3(576), 256, 0, stream>>>(rb2_w1, A3, 147456);
    d7_cast<<<dim3(576), 256, 0, stream>>>(rb2_w2, A4, 147456);
    d7_wbuild<<<dim3(128), 256, 0, stream>>>(pamb_w, pam_w, paa_w, pamb_b, pam_b, paa_b,
                                             pamb_a, pam_a, paa_a, W1, W2, b1v, a1v, b2v, a2v);

    d7_maxpool<<<dim3(16, 64, 2), 256, 0, stream>>>(x, h0f);
    conv(h0f, A0, 64, bb0_b, bb0_a, 1, nullptr, h1f);
    conv(h1f, A1, 128, rb1_b1, nullptr, 2, nullptr, tbuf);
    conv(tbuf, A2, 128, rb1_b2, nullptr, 0, h1f, h2f);

    d7_resize<57><<<dim3(13, 128, 2), 256, 0, stream>>>(h2f, refb, refbs);
    d7_resize<51><<<dim3(11, 128, 2), 256, 0, stream>>>(h2f, refb + 3249L * 128, refbs);
    d7_resize<44><<<dim3(8, 128, 2), 256, 0, stream>>>(h2f, refb + 5850L * 128, refbs);

    // p-major bf16 operands for the fused 1x1-conv GEMMs (per-level transpose)
    hipMemsetAsync(refbT, 0, 2ull * rbTbs * 2, stream);
    d7_t32<<<dim3(128, 4, 2), 256, 0, stream>>>(h2f, h2bs, 4096, h2T, 4096L * 128);
    d7_t32<<<dim3(102, 4, 2), 256, 0, stream>>>(refb, refbs, 3249, refbT, rbTbs);
    d7_t32<<<dim3(82, 4, 2), 256, 0, stream>>>(refb + 3249L * 128, refbs, 2601, refbT + 3249L * 128, rbTbs);
    d7_t32<<<dim3(61, 4, 2), 256, 0, stream>>>(refb + 5850L * 128, refbs, 1936, refbT + 5850L * 128, rbTbs);

    // all 1x1 convs as two GEMMs
    d7_gemm<<<dim3(32, 2, 2), 256, 0, stream>>>(W1, h2T, 4096, 128, 128, 2, 1,
        0, 4096L * 128, b1v, a1v, 3, nullptr, 0,
        nullptr, 0, cOut1, cO1bs, cT1, 256, cT1bs, nullptr, 0, 0);
    d7_gemm<<<dim3(61, 2, 2), 256, 0, stream>>>(W2, refbT, 7808, 128, 128, 2, 1,
        0, rbTbs, b2v, a2v, 3, nullptr, 0,
        nullptr, 0, cOut2, cO2bs, cT2, 256, cT2bs, nullptr, 0, 0);

    // scatter into padded attention layouts (+ fused s2 for refmT)
    hipMemsetAsync(refmT, 0, 2ull * LP * 64 * 2, stream);
    hipMemsetAsync(baseA, 0, 2ull * 128 * LP * 2, stream);
    hipMemsetAsync(s2b, 0, 2ull * LP * 4, stream);
    d7_scK<<<dim3(128, 1, 2), 256, 0, stream>>>(cT1, cT1bs, 256, 0, 0, 4096, 64, 64, -65, mbT, mbTbs, nullptr);
    d7_scK<<<dim3(128, 1, 2), 256, 0, stream>>>(cT1, cT1bs, 256, 64, 0, 4096, 64, 72, 0, refmT, rmTbs, s2b);
    d7_scK<<<dim3(102, 1, 2), 256, 0, stream>>>(cT2, cT2bs, 256, 0, 0, 3249, 57, 64, 4752, refmT, rmTbs, s2b);
    d7_scK<<<dim3(82, 1, 2), 256, 0, stream>>>(cT2, cT2bs, 256, 0, 3249, 2601, 51, 56, 8528, refmT, rmTbs, s2b);
    d7_scK<<<dim3(61, 1, 2), 256, 0, stream>>>(cT2, cT2bs, 256, 0, 5850, 1936, 44, 48, 11496, refmT, rmTbs, s2b);
    d7_scR<<<dim3(16, 128, 2), 256, 0, stream>>>(cOut1, cO1bs, 4096, 128, 0, 4096, 64, 72, 0, baseA, baBS);
    d7_scR<<<dim3(13, 128, 2), 256, 0, stream>>>(cOut2, cO2bs, 7808, 64, 0, 3249, 57, 64, 4752, baseA, baBS);
    d7_scR<<<dim3(11, 128, 2), 256, 0, stream>>>(cOut2, cO2bs, 7808, 64, 3249, 2601, 51, 56, 8528, baseA, baBS);
    d7_scR<<<dim3(8, 128, 2), 256, 0, stream>>>(cOut2, cO2bs, 7808, 64, 5850, 1936, 44, 48, 11496, baseA, baBS);

    d7_rnormk<<<dim3(54, 1, 2), 256, 0, stream>>>(s2b, rnorm);

    for (int b = 0; b < 2; ++b) {
        // S0T[p][l'] via transposed 8B stores: A=refmT (M=LP), B=mbT (N=4096)
        d7_gemm<<<dim3(32, 108, 1), 256, 0, stream>>>(refmT + b * rmTbs, mbT + b * mbTbs,
            4096, 64, 64, 108, 1, 0, 0, nullptr, nullptr, 0, nullptr, 0,
            nullptr, 0, nullptr, 0, S0T, LP, 0, nullptr, 0, 0);
        d7_st1<<<dim3(7, 4096), 256, 0, stream>>>(S0T, scT, rnorm + (size_t)b * LP);
        d7_stats<<<dim3(4096), 256, 0, stream>>>(scT, statM);
        d7_st2<<<dim3(7, 4096), 256, 0, stream>>>(scT, statM, rnorm + (size_t)b * LP, gT);
        // out_pa = h2f + 0.25 * baseA · gT^T  (split-K = 12, bf16 partials)
        d7_gemm<<<dim3(32, 12, 1), 256, 0, stream>>>(baseA + b * baBS, gT,
            4096, LP, LP / 12, 1, 12, 0, 0, nullptr, nullptr, 0, nullptr, 0,
            nullptr, 0, nullptr, 0, nullptr, 0, 0, parts, pMN, 1);
        d7_epi<<<dim3(2048, 1, 1), 256, 0, stream>>>(parts, 12, pMN, 0,
            nullptr, nullptr, 0, h2f + b * h2bs, 0, 0.25f, paf + b * h2bs, 0, (int)pMN, 1);
    }

    conv(paf, A3, 128, rb2_b1, nullptr, 2, nullptr, tbuf);
    conv(tbuf, A4, 128, rb2_b2, nullptr, 0, paf, out);
}

// Round 10
// 953.488 us; speedup vs baseline: 1.0851x; 1.0553x over previous
//
#include <hip/hip_runtime.h>

typedef unsigned short u16;
typedef __attribute__((ext_vector_type(8))) __bf16 bf16x8;
typedef __attribute__((ext_vector_type(8))) unsigned short ushort8;
typedef __attribute__((ext_vector_type(4))) float f32x4;

__device__ __forceinline__ float bf2f(u16 u) { return __uint_as_float(((unsigned)u) << 16); }
__device__ __forceinline__ u16 f2bf(float f) {
    unsigned x = __float_as_uint(f);
    x += 0x7fffu + ((x >> 16) & 1u);
    return (u16)(x >> 16);
}
__device__ __forceinline__ u16 f2h16(float f) {
    _Float16 h = (_Float16)f; u16 r; __builtin_memcpy(&r, &h, 2); return r;
}
__device__ __forceinline__ float h162f(u16 u) {
    _Float16 h; __builtin_memcpy(&h, &u, 2); return (float)h;
}

// Padded l-space: per-scale (HS+2) rows x W' cols with zero border, W' mult of 8.
// scale0: HS=64 W=72 off=0      (66*72=4752)
// scale1: HS=57 W=64 off=4752   (59*64=3776)
// scale2: HS=51 W=56 off=8528   (53*56=2968)
// scale3: HS=44 W=48 off=11496  (46*48=2208) -> 13704, dead zone to LP=13824
#define LP 13824

// ---------------------------------------------------------------------------
// GEMM: C[M,N] = A[M,K] * B[N,K]^T  (bf16 in, fp32 acc), 128x128 tile, BK=32.
// ---------------------------------------------------------------------------
__global__ __launch_bounds__(256) void d7_gemm(
    const u16* __restrict__ A, const u16* __restrict__ B,
    int N, int K, int kLen, int mTiles, int S,
    long aBS, long bBS,
    const float* __restrict__ bias, const float* __restrict__ alpha, int act,
    const float* __restrict__ resid, long residBS,
    float* __restrict__ outF, long oFBS,
    u16* __restrict__ outB, long oBBS,
    u16* __restrict__ outT, int ldT, long oTBS,
    float* __restrict__ outP, long pMN, int pBf)
{
    __shared__ u16 As[128 * 40];
    __shared__ u16 Bs[128 * 40];

    const int tid = threadIdx.x;
    const int wv = tid >> 6, lane = tid & 63;
    const int wm = wv >> 1, wn = wv & 1;
    const int bn = blockIdx.x;
    const int bm = blockIdx.y % mTiles;
    const int ks = blockIdx.y / mTiles;
    const int z  = blockIdx.z;
    const int kStart = ks * kLen;

    const int srow = tid >> 1;
    const int soff = (tid & 1) * 16;
    const u16* gA = A + z * aBS + (size_t)(bm * 128 + srow) * K + kStart + soff;
    const u16* gB = B + z * bBS + (size_t)(bn * 128 + srow) * K + kStart + soff;
    u16* lA = &As[srow * 40 + soff];
    u16* lB = &Bs[srow * 40 + soff];

    f32x4 acc[4][4] = {};

    for (int k0 = 0; k0 < kLen; k0 += 32) {
        __syncthreads();
        ((uint4*)lA)[0] = ((const uint4*)gA)[0];
        ((uint4*)lA)[1] = ((const uint4*)gA)[1];
        ((uint4*)lB)[0] = ((const uint4*)gB)[0];
        ((uint4*)lB)[1] = ((const uint4*)gB)[1];
        gA += 32; gB += 32;
        __syncthreads();

        bf16x8 a[4], b[4];
        #pragma unroll
        for (int mt = 0; mt < 4; ++mt)
            a[mt] = *reinterpret_cast<const bf16x8*>(&As[(wm * 64 + mt * 16 + (lane & 15)) * 40 + (lane >> 4) * 8]);
        #pragma unroll
        for (int nt = 0; nt < 4; ++nt)
            b[nt] = *reinterpret_cast<const bf16x8*>(&Bs[(wn * 64 + nt * 16 + (lane & 15)) * 40 + (lane >> 4) * 8]);
        #pragma unroll
        for (int mt = 0; mt < 4; ++mt)
            #pragma unroll
            for (int nt = 0; nt < 4; ++nt)
                acc[mt][nt] = __builtin_amdgcn_mfma_f32_16x16x32_bf16(a[mt], b[nt], acc[mt][nt], 0, 0, 0);
    }

    if (outP) {
        const size_t pbase = ((size_t)z * S + ks) * pMN;
        #pragma unroll
        for (int mt = 0; mt < 4; ++mt) {
            const int mg = bm * 128 + wm * 64 + mt * 16 + ((lane >> 4) << 2);
            #pragma unroll
            for (int nt = 0; nt < 4; ++nt) {
                const int ng = bn * 128 + wn * 64 + nt * 16 + (lane & 15);
                if (pBf) {
                    u16* pp = (u16*)outP + pbase;
                    #pragma unroll
                    for (int r = 0; r < 4; ++r)
                        pp[(size_t)(mg + r) * N + ng] = f2bf(acc[mt][nt][r]);
                } else {
                    float* pp = outP + pbase;
                    #pragma unroll
                    for (int r = 0; r < 4; ++r)
                        pp[(size_t)(mg + r) * N + ng] = acc[mt][nt][r];
                }
            }
        }
        return;
    }

    const float avalS = (act == 1) ? alpha[0] : 0.0f;
    #pragma unroll
    for (int mt = 0; mt < 4; ++mt) {
        const int mg = bm * 128 + wm * 64 + mt * 16 + ((lane >> 4) << 2);
        float bv[4] = {0.f, 0.f, 0.f, 0.f}, av[4];
        if (bias) {
            #pragma unroll
            for (int r = 0; r < 4; ++r) bv[r] = bias[mg + r];
        }
        if (act == 3) {
            #pragma unroll
            for (int r = 0; r < 4; ++r) av[r] = alpha[mg + r];
        }
        #pragma unroll
        for (int nt = 0; nt < 4; ++nt) {
            const int ng = bn * 128 + wn * 64 + nt * 16 + (lane & 15);
            float v[4];
            #pragma unroll
            for (int r = 0; r < 4; ++r) {
                float t = acc[mt][nt][r] + bv[r];
                if (act == 1) t = (t >= 0.f) ? t : avalS * t;
                else if (act == 2) t = fmaxf(t, 0.f);
                else if (act == 3) t = (t >= 0.f) ? t : av[r] * t;
                if (resid) t += resid[z * residBS + (size_t)(mg + r) * N + ng];
                v[r] = t;
            }
            if (outF) {
                #pragma unroll
                for (int r = 0; r < 4; ++r) outF[z * oFBS + (size_t)(mg + r) * N + ng] = v[r];
            }
            if (outB) {
                #pragma unroll
                for (int r = 0; r < 4; ++r) outB[z * oBBS + (size_t)(mg + r) * N + ng] = f2bf(v[r]);
            }
            if (outT) {
                unsigned long long pk = (unsigned long long)f2bf(v[0])
                    | ((unsigned long long)f2bf(v[1]) << 16)
                    | ((unsigned long long)f2bf(v[2]) << 32)
                    | ((unsigned long long)f2bf(v[3]) << 48);
                *reinterpret_cast<unsigned long long*>(outT + z * oTBS + (size_t)ng * ldT + mg) = pk;
            }
        }
    }
}

// split-K reduce + bias/act/resid epilogue; N fixed 4096 (m = i>>12)
__global__ __launch_bounds__(256) void d7_epi(
    const void* __restrict__ parts, int S, long sStride, long bStride,
    const float* __restrict__ bias, const float* __restrict__ alpha, int act,
    const float* __restrict__ resid, long residBS, float scale,
    float* __restrict__ out, long outBS, int total, int pBf)
{
    int i = blockIdx.x * 256 + threadIdx.x;
    if (i >= total) return;
    int b = blockIdx.z;
    float s = 0.f;
    if (pBf) {
        const u16* p = (const u16*)parts + b * bStride + i;
        for (int t = 0; t < S; ++t) s += bf2f(p[(size_t)t * sStride]);
    } else {
        const float* p = (const float*)parts + b * bStride + i;
        for (int t = 0; t < S; ++t) s += p[(size_t)t * sStride];
    }
    s *= scale;
    if (bias) s += bias[i >> 12];
    if (act == 1) { float a = alpha[0]; s = (s >= 0.f) ? s : a * s; }
    else if (act == 2) s = fmaxf(s, 0.f);
    if (resid) s += resid[b * residBS + i];
    out[b * outBS + i] = s;
}

// ---------------------------------------------------------------------------
__global__ __launch_bounds__(256) void d7_cast(const float* __restrict__ src, u16* __restrict__ dst, int n) {
    int i = blockIdx.x * 256 + threadIdx.x;
    if (i < n) dst[i] = f2bf(src[i]);
}

__global__ __launch_bounds__(256) void d7_wbuild(
    const float* __restrict__ pamb_w, const float* __restrict__ pam_w, const float* __restrict__ paa_w,
    const float* __restrict__ pamb_b, const float* __restrict__ pam_b, const float* __restrict__ paa_b,
    const float* __restrict__ pamb_a, const float* __restrict__ pam_a, const float* __restrict__ paa_a,
    u16* __restrict__ W1, u16* __restrict__ W2,
    float* __restrict__ b1, float* __restrict__ a1,
    float* __restrict__ b2, float* __restrict__ a2)
{
    int i = blockIdx.x * 256 + threadIdx.x;
    if (i < 256 * 128) {
        int r = i >> 7, c = i & 127;
        float w1 = (r < 64) ? pamb_w[r * 128 + c] : (r < 128) ? pam_w[(r - 64) * 128 + c] : paa_w[(r - 128) * 128 + c];
        W1[i] = f2bf(w1);
        float w2 = (r < 64) ? pam_w[r * 128 + c] : (r < 192) ? paa_w[(r - 64) * 128 + c] : 0.f;
        W2[i] = f2bf(w2);
    }
    if (i < 256) {
        int r = i;
        b1[r] = (r < 64) ? pamb_b[r] : (r < 128) ? pam_b[r - 64] : paa_b[r - 128];
        a1[r] = (r < 64) ? pamb_a[0] : (r < 128) ? pam_a[0] : paa_a[0];
        b2[r] = (r < 64) ? pam_b[r] : (r < 192) ? paa_b[r - 64] : 0.f;
        a2[r] = (r < 64) ? pam_a[0] : (r < 192) ? paa_a[0] : 0.f;
    }
}

__global__ __launch_bounds__(256) void d7_maxpool(const float* __restrict__ x, float* __restrict__ out) {
    int p = blockIdx.x * 256 + threadIdx.x;
    int c = blockIdx.y, b = blockIdx.z;
    int oh = p >> 6, ow = p & 63;
    const float* ip = x + ((size_t)b * 64 + c) * 16384;
    float v0 = ip[(2 * oh) * 128 + 2 * ow];
    float v1 = ip[(2 * oh) * 128 + 2 * ow + 1];
    float v2 = ip[(2 * oh + 1) * 128 + 2 * ow];
    float v3 = ip[(2 * oh + 1) * 128 + 2 * ow + 1];
    out[((size_t)b * 64 + c) * 4096 + p] = fmaxf(fmaxf(v0, v1), fmaxf(v2, v3));
}

__global__ __launch_bounds__(256) void d7_im2col(const float* __restrict__ img, u16* __restrict__ patT,
                                                 int Cin, long inBS, long outBS) {
    int K = Cin * 9;
    int k = blockIdx.x * 256 + threadIdx.x;
    if (k >= K) return;
    int p = blockIdx.y, b = blockIdx.z;
    int c = k / 9, k9 = k - c * 9;
    int h = p >> 6, w = p & 63;
    int y = h + k9 / 3 - 1, x = w + (k9 % 3) - 1;
    const float* ip = img + b * inBS;
    float v = (y >= 0 && y < 64 && x >= 0 && x < 64) ? ip[(size_t)c * 4096 + y * 64 + x] : 0.f;
    patT[b * outBS + (size_t)p * K + k] = f2bf(v);
}

// transpose-cast: in fp32 [128][P] -> out bf16 [p][128]
__global__ __launch_bounds__(256) void d7_t32(const float* __restrict__ in, long inBS, int P,
                                              u16* __restrict__ out, long outBS) {
    __shared__ float tile[32][33];
    int p0 = blockIdx.x * 32, c0 = blockIdx.y * 32, b = blockIdx.z;
    int tx = threadIdx.x & 31, ty = threadIdx.x >> 5;
    const float* ip = in + b * inBS;
    #pragma unroll
    for (int i = 0; i < 32; i += 8) {
        int c = c0 + ty + i, p = p0 + tx;
        tile[ty + i][tx] = (p < P) ? ip[(size_t)c * P + p] : 0.f;
    }
    __syncthreads();
    u16* op = out + b * outBS;
    #pragma unroll
    for (int i = 0; i < 32; i += 8) {
        int p = p0 + ty + i, c = c0 + tx;
        if (p < P) op[(size_t)p * 128 + c] = f2bf(tile[tx][ty + i]);
    }
}

// scatter K-major 64-wide rows (+ optional fused s2)
__global__ __launch_bounds__(256) void d7_scK(const u16* __restrict__ cT, long cBS, int ldC, int colBase,
                                              int pOff, int P, int HS, int Wp, int off,
                                              u16* __restrict__ dst, long dBS,
                                              float* __restrict__ s2out) {
    int t = blockIdx.x * 256 + threadIdx.x;
    int p = t >> 3, cg = t & 7;
    if (p >= P) return;
    int b = blockIdx.z;
    ushort8 v = *reinterpret_cast<const ushort8*>(cT + b * cBS + (size_t)(pOff + p) * ldC + colBase + cg * 8);
    int h = p / HS, w = p - h * HS;
    int lp = off + (h + 1) * Wp + w + 1;
    *reinterpret_cast<ushort8*>(dst + b * dBS + (size_t)lp * 64 + cg * 8) = v;
    if (s2out) {
        float ss = 0.f;
        #pragma unroll
        for (int i = 0; i < 8; ++i) { float f = bf2f(v[i]); ss += f * f; }
        ss += __shfl_xor(ss, 1);
        ss += __shfl_xor(ss, 2);
        ss += __shfl_xor(ss, 4);
        if (cg == 0) s2out[(size_t)b * LP + lp] = ss;
    }
}

__global__ __launch_bounds__(256) void d7_scR(const u16* __restrict__ cO, long cBS, int ldC, int rowBase,
                                              int pOff, int P, int HS, int Wp, int off,
                                              u16* __restrict__ dst, long dBS) {
    int p = blockIdx.x * 256 + threadIdx.x;
    if (p >= P) return;
    int co = blockIdx.y, b = blockIdx.z;
    u16 v = cO[b * cBS + (size_t)(rowBase + co) * ldC + pOff + p];
    int h = p / HS, w = p - h * HS;
    int lp = off + (h + 1) * Wp + w + 1;
    dst[b * dBS + (size_t)co * LP + lp] = v;
}

// jax.image.resize bilinear antialias, 64 -> OS
template <int OS>
__device__ __forceinline__ void d7_taps(int o, int& i0, float w3[3]) {
    const float inv = 64.0f / OS;
    float s = (o + 0.5f) * inv - 0.5f;
    i0 = (int)ceilf(s - inv);
    float wsum = 0.f;
    #pragma unroll
    for (int t = 0; t < 3; ++t) {
        int y = i0 + t;
        float wt = 1.0f - fabsf((float)y - s) / inv;
        wt = (wt > 0.f && y >= 0 && y < 64) ? wt : 0.f;
        w3[t] = wt; wsum += wt;
    }
    float r = 1.0f / wsum;
    w3[0] *= r; w3[1] *= r; w3[2] *= r;
}

template <int OS>
__global__ __launch_bounds__(256) void d7_resize(const float* __restrict__ in, float* __restrict__ out, long out_bs) {
    int p = blockIdx.x * 256 + threadIdx.x;
    if (p >= OS * OS) return;
    int c = blockIdx.y, b = blockIdx.z;
    int oh = p / OS, ow = p - oh * OS;
    const float* img = in + ((size_t)b * 128 + c) * 4096;
    int y0, x0; float wy[3], wx[3];
    d7_taps<OS>(oh, y0, wy);
    d7_taps<OS>(ow, x0, wx);
    float sum = 0.f;
    #pragma unroll
    for (int iy = 0; iy < 3; ++iy) {
        if (wy[iy] <= 0.f) continue;
        float rs = 0.f;
        #pragma unroll
        for (int ix = 0; ix < 3; ++ix) {
            if (wx[ix] <= 0.f) continue;
            rs += wx[ix] * img[(y0 + iy) * 64 + (x0 + ix)];
        }
        sum += wy[iy] * rs;
    }
    out[(size_t)b * out_bs + (size_t)c * OS * OS + p] = sum;
}

__device__ __forceinline__ int d7_scaleW(int l) {
    return (l < 4752) ? 72 : (l < 8528) ? 64 : (l < 11496) ? 56 : 48;
}

// rnorm[l'] = interior ? (10*log2e)/max(sqrt(9-tap sum of s2),1e-4) : 0
__global__ __launch_bounds__(256) void d7_rnormk(const float* __restrict__ s2, float* __restrict__ rnorm) {
    int l = blockIdx.x * 256 + threadIdx.x;
    if (l >= LP) return;
    int zb = blockIdx.z;
    int off, W, HS;
    if (l < 4752)       { off = 0;     W = 72; HS = 64; }
    else if (l < 8528)  { off = 4752;  W = 64; HS = 57; }
    else if (l < 11496) { off = 8528;  W = 56; HS = 51; }
    else                { off = 11496; W = 48; HS = 44; }
    int li = l - off, y = li / W, x = li - y * W;
    float v = 0.f;
    if (y >= 1 && y <= HS && x >= 1 && x <= HS) {
        const float* s = s2 + (size_t)zb * LP;
        float a = 0.f;
        #pragma unroll
        for (int dy = -1; dy <= 1; ++dy)
            #pragma unroll
            for (int dx = -1; dx <= 1; ++dx)
                a += s[l + dy * W + dx];
        v = 14.426950408889634f / fmaxf(sqrtf(a), 1e-4f);
    }
    rnorm[(size_t)zb * LP + l] = v;
}

// stencil1 + per-block softmax partials. Aligned 16B loads + lane shuffles for +/-1.
// scT fp16 log2-domain (pads -1e4). part[p*7+bx] = (m_blk, sum exp2(v - m_blk)).
__global__ __launch_bounds__(256) void d7_st1(const u16* __restrict__ in, u16* __restrict__ out,
                                              const float* __restrict__ rnorm,
                                              float2* __restrict__ part) {
    const int tid = threadIdx.x, wvi = tid >> 6, lane = tid & 63;
    int vg = blockIdx.x * 256 + tid;
    const bool active = vg < LP / 8;
    int l8 = vg << 3;
    int p = blockIdx.y;
    int h = p >> 6, w = p & 63;
    float vals[8];
    if (active) {
        int W = d7_scaleW(l8);
        float acc[8] = {0.f, 0.f, 0.f, 0.f, 0.f, 0.f, 0.f, 0.f};
        #pragma unroll
        for (int a = -1; a <= 1; ++a) {
            int ph = h + a;
            if ((unsigned)ph >= 64u) continue;
            const u16* rb = in + (size_t)(p + a * 64) * LP + l8 + a * W;   // aligned base (b=0 row)
            {
                ushort8 v = *reinterpret_cast<const ushort8*>(rb);
                #pragma unroll
                for (int i = 0; i < 8; ++i) acc[i] += bf2f(v[i]);
            }
            if (w - 1 >= 0) {       // b=-1: row -LP, elements shifted right by 1
                const u16* r1 = rb - LP;
                ushort8 v = *reinterpret_cast<const ushort8*>(r1);
                int up = __shfl_up((int)v[7], 1);
                u16 e = (lane == 0) ? r1[-1] : (u16)up;
                acc[0] += bf2f(e);
                #pragma unroll
                for (int i = 1; i < 8; ++i) acc[i] += bf2f(v[i - 1]);
            }
            if (w + 1 < 64) {       // b=+1: row +LP, elements shifted left by 1
                const u16* r1 = rb + LP;
                ushort8 v = *reinterpret_cast<const ushort8*>(r1);
                int dn = __shfl_down((int)v[0], 1);
                u16 e = (lane == 63) ? r1[8] : (u16)dn;
                #pragma unroll
                for (int i = 0; i < 7; ++i) acc[i] += bf2f(v[i + 1]);
                acc[7] += bf2f(e);
            }
        }
        const float4 rn0 = *reinterpret_cast<const float4*>(rnorm + l8);
        const float4 rn1 = *reinterpret_cast<const float4*>(rnorm + l8 + 4);
        float rn[8] = {rn0.x, rn0.y, rn0.z, rn0.w, rn1.x, rn1.y, rn1.z, rn1.w};
        ushort8 res;
        #pragma unroll
        for (int i = 0; i < 8; ++i) {
            u16 q = f2h16((rn[i] != 0.f) ? acc[i] * rn[i] : -1e4f);
            res[i] = q;
            vals[i] = h162f(q);     // post-rounding values: matches what st2 reads
        }
        *reinterpret_cast<ushort8*>(out + (size_t)p * LP + l8) = res;
    } else {
        #pragma unroll
        for (int i = 0; i < 8; ++i) vals[i] = -1e4f;
    }
    // block-local softmax partials
    float m = vals[0];
    #pragma unroll
    for (int i = 1; i < 8; ++i) m = fmaxf(m, vals[i]);
    #pragma unroll
    for (int o = 1; o < 64; o <<= 1) m = fmaxf(m, __shfl_xor(m, o));
    __shared__ float red[4];
    if (lane == 0) red[wvi] = m;
    __syncthreads();
    m = fmaxf(fmaxf(red[0], red[1]), fmaxf(red[2], red[3]));
    __syncthreads();
    float s = 0.f;
    #pragma unroll
    for (int i = 0; i < 8; ++i) s += __builtin_amdgcn_exp2f(vals[i] - m);
    #pragma unroll
    for (int o = 1; o < 64; o <<= 1) s += __shfl_xor(s, o);
    if (lane == 0) red[wvi] = s;
    __syncthreads();
    if (tid == 0) {
        float Z = red[0] + red[1] + red[2] + red[3];
        part[p * 7 + blockIdx.x] = make_float2(m, Z);
    }
}

// combine 7 per-block partials per row: statM[p] = m + log2(sum s_i * exp2(m_i - m))
__global__ __launch_bounds__(256) void d7_comb(const float2* __restrict__ part, float* __restrict__ statM) {
    int p = blockIdx.x * 256 + threadIdx.x;
    if (p >= 4096) return;
    const float2* q = part + p * 7;
    float2 e[7];
    #pragma unroll
    for (int t = 0; t < 7; ++t) e[t] = q[t];
    float m = e[0].x;
    #pragma unroll
    for (int t = 1; t < 7; ++t) m = fmaxf(m, e[t].x);
    float Z = 0.f;
    #pragma unroll
    for (int t = 0; t < 7; ++t) Z += e[t].y * __builtin_amdgcn_exp2f(e[t].x - m);
    statM[p] = m + __log2f(Z);
}

// stencil2 (R7 form: aligned vector loads, register-indexed +/-1, scalar edge loads):
// gT[p][l'] = interior ? sum_taps exp2(v - M'_r) : 0
__global__ __launch_bounds__(256) void d7_st2(const u16* __restrict__ in,
                                              const float* __restrict__ statM,
                                              const float* __restrict__ rnorm,
                                              u16* __restrict__ out) {
    int vg = blockIdx.x * 256 + threadIdx.x;
    if (vg >= LP / 8) return;
    int l8 = vg << 3;
    int p = blockIdx.y;
    int h = p >> 6, w = p & 63;
    int W = d7_scaleW(l8);
    float acc[8] = {0.f, 0.f, 0.f, 0.f, 0.f, 0.f, 0.f, 0.f};
    #pragma unroll
    for (int a = -1; a <= 1; ++a) {
        int ph = h + a;
        if ((unsigned)ph >= 64u) continue;
        #pragma unroll
        for (int b = -1; b <= 1; ++b) {
            int pw = w + b;
            if ((unsigned)pw >= 64u) continue;
            int r = p + a * 64 + b;
            float M = statM[r];
            const u16* rp = in + (size_t)r * LP + l8 + a * W;
            ushort8 v = *reinterpret_cast<const ushort8*>(rp);
            if (b == 0) {
                #pragma unroll
                for (int i = 0; i < 8; ++i) acc[i] += __builtin_amdgcn_exp2f(h162f(v[i]) - M);
            } else if (b == -1) {
                acc[0] += __builtin_amdgcn_exp2f(h162f(rp[-1]) - M);
                #pragma unroll
                for (int i = 1; i < 8; ++i) acc[i] += __builtin_amdgcn_exp2f(h162f(v[i - 1]) - M);
            } else {
                acc[7] += __builtin_amdgcn_exp2f(h162f(rp[8]) - M);
                #pragma unroll
                for (int i = 0; i < 7; ++i) acc[i] += __builtin_amdgcn_exp2f(h162f(v[i + 1]) - M);
            }
        }
    }
    const float4 rn0 = *reinterpret_cast<const float4*>(rnorm + l8);
    const float4 rn1 = *reinterpret_cast<const float4*>(rnorm + l8 + 4);
    float rn[8] = {rn0.x, rn0.y, rn0.z, rn0.w, rn1.x, rn1.y, rn1.z, rn1.w};
    ushort8 res;
    #pragma unroll
    for (int i = 0; i < 8; ++i)
        res[i] = f2bf((rn[i] != 0.f) ? acc[i] : 0.f);
    *reinterpret_cast<ushort8*>(out + (size_t)p * LP + l8) = res;
}

// ---------------------------------------------------------------------------
extern "C" void kernel_launch(void* const* d_in, const int* in_sizes, int n_in,
                              void* d_out, int out_size, void* d_ws, size_t ws_size,
                              hipStream_t stream) {
    const float* x      = (const float*)d_in[0];
    const float* bb0_w  = (const float*)d_in[1];
    const float* bb0_b  = (const float*)d_in[2];
    const float* bb0_a  = (const float*)d_in[3];
    const float* rb1_w1 = (const float*)d_in[4];
    const float* rb1_b1 = (const float*)d_in[5];
    const float* rb1_w2 = (const float*)d_in[6];
    const float* rb1_b2 = (const float*)d_in[7];
    const float* pamb_w = (const float*)d_in[8];
    const float* pamb_b = (const float*)d_in[9];
    const float* pamb_a = (const float*)d_in[10];
    const float* pam_w  = (const float*)d_in[11];
    const float* pam_b  = (const float*)d_in[12];
    const float* pam_a  = (const float*)d_in[13];
    const float* paa_w  = (const float*)d_in[14];
    const float* paa_b  = (const float*)d_in[15];
    const float* paa_a  = (const float*)d_in[16];
    const float* rb2_w1 = (const float*)d_in[17];
    const float* rb2_b1 = (const float*)d_in[18];
    const float* rb2_w2 = (const float*)d_in[19];
    const float* rb2_b2 = (const float*)d_in[20];
    float* out = (float*)d_out;
    (void)in_sizes; (void)n_in; (void)out_size; (void)ws_size;

    char* wp = (char*)d_ws;
    auto alloc = [&](size_t nbytes) { void* p = wp; wp += (nbytes + 255) & ~(size_t)255; return p; };
    const size_t BIG = 4096ull * LP * 2;             // 113 MB
    const size_t PAD = 40960;                        // front slack for stencil edge reads
    char* big1r  = (char*)alloc(BIG + PAD);
    char* big2r  = (char*)alloc(BIG + PAD);
    float* h0f   = (float*)alloc(2ull * 64 * 4096 * 4);
    float* h1f   = (float*)alloc(2ull * 128 * 4096 * 4);
    float* h2f   = (float*)alloc(2ull * 128 * 4096 * 4);
    float* paf   = (float*)alloc(2ull * 128 * 4096 * 4);
    float* tbuf  = (float*)alloc(2ull * 128 * 4096 * 4);
    u16* mbT     = (u16*)alloc(2ull * 4096 * 64 * 2);
    u16* refmT   = (u16*)alloc(2ull * LP * 64 * 2);
    u16* baseA   = (u16*)alloc(2ull * 128 * LP * 2);
    float* s2b   = (float*)alloc(2ull * LP * 4);
    float* rnorm = (float*)alloc(2ull * LP * 4);
    float* statM = (float*)alloc(4096ull * 4);
    float2* partb = (float2*)alloc(4096ull * 7 * 8);
    u16* W1      = (u16*)alloc(256ull * 128 * 2);
    u16* W2      = (u16*)alloc(256ull * 128 * 2);
    float* b1v   = (float*)alloc(256 * 4);
    float* a1v   = (float*)alloc(256 * 4);
    float* b2v   = (float*)alloc(256 * 4);
    float* a2v   = (float*)alloc(256 * 4);
    u16* A0      = (u16*)alloc(73728ull * 2);
    u16* A1      = (u16*)alloc(147456ull * 2);
    u16* A2      = (u16*)alloc(147456ull * 2);
    u16* A3      = (u16*)alloc(147456ull * 2);
    u16* A4      = (u16*)alloc(147456ull * 2);
    // Views inside the big buffers (lifetime-disjoint phases):
    u16* patT    = (u16*)big1r;
    u16* h2T     = (u16*)big1r;                          // [2][4096][128]
    u16* refbT   = (u16*)(big1r + (4ull << 20));         // [2][7808][128]
    u16* S0T     = (u16*)(big1r + 32768);                // stencil bufs: 32KB front slack
    u16* gT      = (u16*)(big1r + 32768);
    float* parts = (float*)big2r;                        // bf16 split-K partials
    u16* cT1     = (u16*)big2r;                          // [2][4096][256]
    u16* cOut1   = (u16*)(big2r + (4ull << 20));         // [2][256][4096]
    u16* cT2     = (u16*)(big2r + (8ull << 20));         // [2][7808][256]
    u16* cOut2   = (u16*)(big2r + (16ull << 20));        // [2][256][7808]
    float* refb  = (float*)(big2r + (26ull << 20));      // [2][level][128][OS^2]
    u16* scT     = (u16*)(big2r + 32768);

    const long h2bs = 128L * 4096;
    const long pMN = 128L * 4096;
    const long refbs = 128L * 7786;
    const long mbTbs = 4096L * 64, rmTbs = (long)LP * 64, baBS = 128L * LP;
    const long cT1bs = 4096L * 256, cO1bs = 256L * 4096;
    const long cT2bs = 7808L * 256, cO2bs = 256L * 7808;
    const long rbTbs = 7808L * 128;

    auto conv = [&](const float* src, const u16* W, int Cin, const float* bias,
                    const float* alpha, int act, const float* resid, float* dst) {
        int K = Cin * 9;
        d7_im2col<<<dim3((K + 255) / 256, 4096, 2), 256, 0, stream>>>(src, patT, Cin, (long)Cin * 4096, 4096L * K);
        d7_gemm<<<dim3(32, 6, 2), 256, 0, stream>>>(W, patT, 4096, K, K / 6, 1, 6,
            0, 4096L * K, nullptr, nullptr, 0, nullptr, 0,
            nullptr, 0, nullptr, 0, nullptr, 0, 0, parts, pMN, 1);
        d7_epi<<<dim3(2048, 1, 2), 256, 0, stream>>>(parts, 6, pMN, 6 * pMN,
            bias, alpha, act, resid, h2bs, 1.0f, dst, h2bs, (int)pMN, 1);
    };

    d7_cast<<<dim3(288), 256, 0, stream>>>(bb0_w, A0, 73728);
    d7_cast<<<dim3(576), 256, 0, stream>>>(rb1_w1, A1, 147456);
    d7_cast<<<dim3(576), 256, 0, stream>>>(rb1_w2, A2, 147456);
    d7_cast<<<dim3(576), 256, 0, stream>>>(rb2_w1, A3, 147456);
    d7_cast<<<dim3(576), 256, 0, stream>>>(rb2_w2, A4, 147456);
    d7_wbuild<<<dim3(128), 256, 0, stream>>>(pamb_w, pam_w, paa_w, pamb_b, pam_b, paa_b,
                                             pamb_a, pam_a, paa_a, W1, W2, b1v, a1v, b2v, a2v);

    d7_maxpool<<<dim3(16, 64, 2), 256, 0, stream>>>(x, h0f);
    conv(h0f, A0, 64, bb0_b, bb0_a, 1, nullptr, h1f);
    conv(h1f, A1, 128, rb1_b1, nullptr, 2, nullptr, tbuf);
    conv(tbuf, A2, 128, rb1_b2, nullptr, 0, h1f, h2f);

    d7_resize<57><<<dim3(13, 128, 2), 256, 0, stream>>>(h2f, refb, refbs);
    d7_resize<51><<<dim3(11, 128, 2), 256, 0, stream>>>(h2f, refb + 3249L * 128, refbs);
    d7_resize<44><<<dim3(8, 128, 2), 256, 0, stream>>>(h2f, refb + 5850L * 128, refbs);

    // p-major bf16 operands for the fused 1x1-conv GEMMs (per-level transpose)
    hipMemsetAsync(refbT, 0, 2ull * rbTbs * 2, stream);
    d7_t32<<<dim3(128, 4, 2), 256, 0, stream>>>(h2f, h2bs, 4096, h2T, 4096L * 128);
    d7_t32<<<dim3(102, 4, 2), 256, 0, stream>>>(refb, refbs, 3249, refbT, rbTbs);
    d7_t32<<<dim3(82, 4, 2), 256, 0, stream>>>(refb + 3249L * 128, refbs, 2601, refbT + 3249L * 128, rbTbs);
    d7_t32<<<dim3(61, 4, 2), 256, 0, stream>>>(refb + 5850L * 128, refbs, 1936, refbT + 5850L * 128, rbTbs);

    // all 1x1 convs as two GEMMs
    d7_gemm<<<dim3(32, 2, 2), 256, 0, stream>>>(W1, h2T, 4096, 128, 128, 2, 1,
        0, 4096L * 128, b1v, a1v, 3, nullptr, 0,
        nullptr, 0, cOut1, cO1bs, cT1, 256, cT1bs, nullptr, 0, 0);
    d7_gemm<<<dim3(61, 2, 2), 256, 0, stream>>>(W2, refbT, 7808, 128, 128, 2, 1,
        0, rbTbs, b2v, a2v, 3, nullptr, 0,
        nullptr, 0, cOut2, cO2bs, cT2, 256, cT2bs, nullptr, 0, 0);

    // scatter into padded attention layouts (+ fused s2 for refmT)
    hipMemsetAsync(refmT, 0, 2ull * LP * 64 * 2, stream);
    hipMemsetAsync(baseA, 0, 2ull * 128 * LP * 2, stream);
    hipMemsetAsync(s2b, 0, 2ull * LP * 4, stream);
    d7_scK<<<dim3(128, 1, 2), 256, 0, stream>>>(cT1, cT1bs, 256, 0, 0, 4096, 64, 64, -65, mbT, mbTbs, nullptr);
    d7_scK<<<dim3(128, 1, 2), 256, 0, stream>>>(cT1, cT1bs, 256, 64, 0, 4096, 64, 72, 0, refmT, rmTbs, s2b);
    d7_scK<<<dim3(102, 1, 2), 256, 0, stream>>>(cT2, cT2bs, 256, 0, 0, 3249, 57, 64, 4752, refmT, rmTbs, s2b);
    d7_scK<<<dim3(82, 1, 2), 256, 0, stream>>>(cT2, cT2bs, 256, 0, 3249, 2601, 51, 56, 8528, refmT, rmTbs, s2b);
    d7_scK<<<dim3(61, 1, 2), 256, 0, stream>>>(cT2, cT2bs, 256, 0, 5850, 1936, 44, 48, 11496, refmT, rmTbs, s2b);
    d7_scR<<<dim3(16, 128, 2), 256, 0, stream>>>(cOut1, cO1bs, 4096, 128, 0, 4096, 64, 72, 0, baseA, baBS);
    d7_scR<<<dim3(13, 128, 2), 256, 0, stream>>>(cOut2, cO2bs, 7808, 64, 0, 3249, 57, 64, 4752, baseA, baBS);
    d7_scR<<<dim3(11, 128, 2), 256, 0, stream>>>(cOut2, cO2bs, 7808, 64, 3249, 2601, 51, 56, 8528, baseA, baBS);
    d7_scR<<<dim3(8, 128, 2), 256, 0, stream>>>(cOut2, cO2bs, 7808, 64, 5850, 1936, 44, 48, 11496, baseA, baBS);

    d7_rnormk<<<dim3(54, 1, 2), 256, 0, stream>>>(s2b, rnorm);

    for (int b = 0; b < 2; ++b) {
        // S0T[p][l'] via transposed 8B stores: A=refmT (M=LP), B=mbT (N=4096)
        d7_gemm<<<dim3(32, 108, 1), 256, 0, stream>>>(refmT + b * rmTbs, mbT + b * mbTbs,
            4096, 64, 64, 108, 1, 0, 0, nullptr, nullptr, 0, nullptr, 0,
            nullptr, 0, nullptr, 0, S0T, LP, 0, nullptr, 0, 0);
        d7_st1<<<dim3(7, 4096), 256, 0, stream>>>(S0T, scT, rnorm + (size_t)b * LP, partb);
        d7_comb<<<dim3(16), 256, 0, stream>>>(partb, statM);
        d7_st2<<<dim3(7, 4096), 256, 0, stream>>>(scT, statM, rnorm + (size_t)b * LP, gT);
        // out_pa = h2f + 0.25 * baseA · gT^T  (split-K = 12, bf16 partials)
        d7_gemm<<<dim3(32, 12, 1), 256, 0, stream>>>(baseA + b * baBS, gT,
            4096, LP, LP / 12, 1, 12, 0, 0, nullptr, nullptr, 0, nullptr, 0,
            nullptr, 0, nullptr, 0, nullptr, 0, 0, parts, pMN, 1);
        d7_epi<<<dim3(2048, 1, 1), 256, 0, stream>>>(parts, 12, pMN, 0,
            nullptr, nullptr, 0, h2f + b * h2bs, 0, 0.25f, paf + b * h2bs, 0, (int)pMN, 1);
    }

    conv(paf, A3, 128, rb2_b1, nullptr, 2, nullptr, tbuf);
    conv(tbuf, A4, 128, rb2_b2, nullptr, 0, paf, out);
}